// Round 1
// baseline (971.012 us; speedup 1.0000x reference)
//
#include <hip/hip_runtime.h>
#include <math.h>

// Problem constants (fixed instance)
namespace {
constexpr int R_ = 32768;     // BS*N rows
constexpr int N_ = 16;
constexpr int NA_ = 30;
constexpr int BSB_ = R_ / N_; // 2048 batches
}

template<int K, int ACT> // ACT: 0=none 1=relu 2=leakyrelu(0.01)
__global__ __launch_bounds__(256)
void gemm_k(const float* __restrict__ A1, int K1,
            const float* __restrict__ A2,
            const float* __restrict__ W, const float* __restrict__ bias,
            float* __restrict__ out, int O)
{
    // C[64 x O] = A[64 x K] * W[O x K]^T + bias, fused activation.
    __shared__ float At[K][68];   // A transposed: At[k][r], pad 68 (16B-aligned rows, conflict-free reads)
    __shared__ float Wt[64][68];  // W chunk transposed: Wt[k][o]
    const int tid = threadIdx.x;
    const int r0 = blockIdx.x * 64;

    for (int idx = tid; idx < 64 * K; idx += 256) {
        int r = idx / K, k = idx - r * K;
        float v;
        if (k < K1) v = A1[(size_t)(r0 + r) * K1 + k];
        else        v = A2[(size_t)(r0 + r) * (K - K1) + (k - K1)];
        At[k][r] = v;
    }

    const int tx = tid & 15, ty = tid >> 4;
    const int ntiles = (O + 63) >> 6;
    for (int ot = 0; ot < ntiles; ++ot) {
        const int o0 = ot * 64;
        float acc[4][4] = {};
        for (int kc = 0; kc < K; kc += 64) {
            __syncthreads(); // At ready (first iter) / Wt consumed (later iters)
            for (int idx = tid; idx < 4096; idx += 256) {
                int ol = idx >> 6, kl = idx & 63;
                int o = o0 + ol;
                Wt[kl][ol] = (o < O) ? W[(size_t)o * K + (kc + kl)] : 0.f;
            }
            __syncthreads();
            #pragma unroll 4
            for (int kl = 0; kl < 64; ++kl) {
                const float4 a4 = *(const float4*)&At[kc + kl][ty * 4];
                const float4 b4 = *(const float4*)&Wt[kl][tx * 4];
                const float av[4] = {a4.x, a4.y, a4.z, a4.w};
                const float bv[4] = {b4.x, b4.y, b4.z, b4.w};
                #pragma unroll
                for (int i = 0; i < 4; ++i)
                    #pragma unroll
                    for (int j = 0; j < 4; ++j)
                        acc[i][j] = fmaf(av[i], bv[j], acc[i][j]);
            }
        }
        const int o = o0 + tx * 4;
        if (o < O) {
            const float4 b4 = *(const float4*)&bias[o];
            const float bb[4] = {b4.x, b4.y, b4.z, b4.w};
            #pragma unroll
            for (int i = 0; i < 4; ++i) {
                const int r = r0 + ty * 4 + i;
                float t[4];
                #pragma unroll
                for (int j = 0; j < 4; ++j) {
                    float v = acc[i][j] + bb[j];
                    if (ACT == 1) v = v > 0.f ? v : 0.f;
                    if (ACT == 2) v = v > 0.f ? v : 0.01f * v;
                    t[j] = v;
                }
                float4 res = {t[0], t[1], t[2], t[3]};
                *(float4*)&out[(size_t)r * O + o] = res;
            }
        }
    }
}

__global__ __launch_bounds__(256)
void gru_kernel(const float* __restrict__ gi, const float* __restrict__ gh,
                const float* __restrict__ hprev, float* __restrict__ h)
{
    int idx = blockIdx.x * 256 + threadIdx.x; // over R*128
    int r = idx >> 7, o = idx & 127;
    size_t base = (size_t)r * 384;
    float ir = gi[base + o], iz = gi[base + 128 + o], inn = gi[base + 256 + o];
    float hr = gh[base + o], hz = gh[base + 128 + o], hn = gh[base + 256 + o];
    float rg = 1.f / (1.f + expf(-(ir + hr)));
    float zg = 1.f / (1.f + expf(-(iz + hz)));
    float ng = tanhf(inn + rg * hn);
    float hp = hprev[idx];
    h[idx] = ng + zg * (hp - ng);
}

__global__ __launch_bounds__(256)
void bn_stats_kernel(const float* __restrict__ t1, float* __restrict__ psum, float* __restrict__ psq)
{
    int f = threadIdx.x;            // feature 0..255
    int rbase = blockIdx.x * (R_ / 256);
    float s = 0.f, ss = 0.f;
    for (int rr = 0; rr < R_ / 256; ++rr) {
        float v = t1[(size_t)(rbase + rr) * 256 + f];
        s += v; ss += v * v;
    }
    psum[blockIdx.x * 256 + f] = s;
    psq[blockIdx.x * 256 + f] = ss;
}

__global__ __launch_bounds__(256)
void bn_final_kernel(const float* __restrict__ psum, const float* __restrict__ psq,
                     const float* __restrict__ g, const float* __restrict__ beta,
                     float* __restrict__ scale, float* __restrict__ shift)
{
    int f = threadIdx.x;
    float s = 0.f, ss = 0.f;
    for (int b = 0; b < 256; ++b) { s += psum[b * 256 + f]; ss += psq[b * 256 + f]; }
    float mean = s / (float)R_;
    float var = ss / (float)R_ - mean * mean; // biased var (ddof=0)
    float istd = rsqrtf(var + 1e-5f);
    float sc = g[f] * istd;
    scale[f] = sc;
    shift[f] = beta[f] - mean * sc;
}

__global__ __launch_bounds__(256)
void bn_act_kernel(const float* __restrict__ t1, const float* __restrict__ scale,
                   const float* __restrict__ shift, float* __restrict__ outv)
{
    int idx = blockIdx.x * 256 + threadIdx.x; // over R*256
    int f = idx & 255;
    float v = t1[idx] * scale[f] + shift[f];
    outv[idx] = v > 0.f ? v : 0.01f * v;
}

__global__ __launch_bounds__(256)
void pm_kernel(const float* __restrict__ t2, const float* __restrict__ eps, float* __restrict__ pm)
{
    int idx = blockIdx.x * 256 + threadIdx.x; // over R*64
    int r = idx >> 6, c = idx & 63;
    float m = t2[(size_t)r * 128 + c];
    float s = t2[(size_t)r * 128 + 64 + c];
    m = fminf(fmaxf(m, -1.f), 1.f);
    s = fminf(fmaxf(s, 0.5f), 1.f);
    pm[idx] = m + s * eps[idx];
}

__global__ __launch_bounds__(256)
void norm_kernel(const float* __restrict__ in, float* __restrict__ outv)
{
    int idx = blockIdx.x * 256 + threadIdx.x; // over R*32, row width 32
    float v = in[idx];
    float ss = v * v;
    #pragma unroll
    for (int m = 16; m >= 1; m >>= 1) ss += __shfl_xor(ss, m); // reduce over 32-lane row group
    float n = sqrtf(ss);
    outv[idx] = v / fmaxf(n, 1e-8f);
}

__global__ __launch_bounds__(256)
void attn_out_kernel(const float* __restrict__ kh, const float* __restrict__ qh,
                     const float* __restrict__ value, const float* __restrict__ hS,
                     const float* __restrict__ le, const float* __restrict__ w2,
                     const float* __restrict__ b2, float* __restrict__ outv)
{
    __shared__ float kh_s[16][32], qh_s[16][32], al_s[16][16], vp_s[16][32];
    __shared__ float val_s[16][64], h_s[16][128], le_s[16][128];
    const int tid = threadIdx.x;
    const size_t rb = (size_t)blockIdx.x * 16;

    for (int idx = tid; idx < 512; idx += 256) {
        kh_s[idx >> 5][idx & 31] = kh[rb * 32 + idx];
        qh_s[idx >> 5][idx & 31] = qh[rb * 32 + idx];
    }
    for (int idx = tid; idx < 1024; idx += 256)
        val_s[idx >> 6][idx & 63] = value[rb * 64 + idx];
    for (int idx = tid; idx < 2048; idx += 256) {
        h_s[idx >> 7][idx & 127] = hS[rb * 128 + idx];
        le_s[idx >> 7][idx & 127] = le[rb * 128 + idx];
    }
    __syncthreads();

    { // logits + softmax over j (incl. diagonal), then zero diagonal
        int i = tid >> 4, j = tid & 15;
        float l = 0.f;
        #pragma unroll
        for (int a = 0; a < 32; ++a) l += kh_s[i][a] * qh_s[j][a];
        float mx = l;
        #pragma unroll
        for (int m = 8; m >= 1; m >>= 1) mx = fmaxf(mx, __shfl_xor(mx, m));
        float e = expf(l - mx);
        float s = e;
        #pragma unroll
        for (int m = 8; m >= 1; m >>= 1) s += __shfl_xor(s, m);
        float a = e / s;
        if (i == j) a = 0.f;
        al_s[i][j] = a;
    }
    __syncthreads();

    // vproj[j][na] = fc2_w[na, 256+64j : 256+64j+64] . value[j]
    for (int task = tid; task < 16 * NA_; task += 256) {
        int na = task >> 4, j = task & 15;
        const float4* wrow = (const float4*)&w2[(size_t)na * 1280 + 256 + j * 64];
        const float4* vrow = (const float4*)&val_s[j][0];
        float acc = 0.f;
        #pragma unroll
        for (int c = 0; c < 16; ++c) {
            float4 wv = wrow[c], vv = vrow[c];
            acc += wv.x * vv.x + wv.y * vv.y + wv.z * vv.z + wv.w * vv.w;
        }
        vp_s[j][na] = acc;
    }
    __syncthreads();

    // out[i][na] = b + fc2_hl . (h,le) + sum_j alpha[i][j]*vproj[j][na]
    for (int task = tid; task < 16 * NA_; task += 256) {
        int i = task / NA_, na = task - i * NA_;
        const float4* wrow = (const float4*)&w2[(size_t)na * 1280];
        const float4* hrow = (const float4*)&h_s[i][0];
        const float4* lerow = (const float4*)&le_s[i][0];
        float acc = b2[na];
        #pragma unroll 8
        for (int c = 0; c < 32; ++c) {
            float4 wv = wrow[c], hv = hrow[c];
            acc += wv.x * hv.x + wv.y * hv.y + wv.z * hv.z + wv.w * hv.w;
        }
        #pragma unroll 8
        for (int c = 0; c < 32; ++c) {
            float4 wv = wrow[32 + c], lv = lerow[c];
            acc += wv.x * lv.x + wv.y * lv.y + wv.z * lv.z + wv.w * lv.w;
        }
        #pragma unroll
        for (int j = 0; j < 16; ++j) acc += al_s[i][j] * vp_s[j][na];
        outv[(rb + i) * NA_ + na] = acc;
    }
}

extern "C" void kernel_launch(void* const* d_in, const int* in_sizes, int n_in,
                              void* d_out, int out_size, void* d_ws, size_t ws_size,
                              hipStream_t stream)
{
    (void)in_sizes; (void)n_in; (void)out_size; (void)ws_size;
    const float* inputs  = (const float*)d_in[0];
    const float* hidden  = (const float*)d_in[1];
    const float* latent  = (const float*)d_in[2];
    const float* eps     = (const float*)d_in[3];
    const float* fc1_w   = (const float*)d_in[4];
    const float* fc1_b   = (const float*)d_in[5];
    const float* w_ih    = (const float*)d_in[6];
    const float* w_hh    = (const float*)d_in[7];
    const float* b_ih    = (const float*)d_in[8];
    const float* b_hh    = (const float*)d_in[9];
    const float* lse_w1  = (const float*)d_in[10];
    const float* lse_b1  = (const float*)d_in[11];
    const float* lse_w2  = (const float*)d_in[12];
    const float* lse_b2  = (const float*)d_in[13];
    const float* me_w1   = (const float*)d_in[14];
    const float* me_b1   = (const float*)d_in[15];
    const float* me_g    = (const float*)d_in[16];
    const float* me_beta = (const float*)d_in[17];
    const float* me_w2   = (const float*)d_in[18];
    const float* me_b2   = (const float*)d_in[19];
    const float* k_w     = (const float*)d_in[20];
    const float* k_b     = (const float*)d_in[21];
    const float* q_w     = (const float*)d_in[22];
    const float* q_b     = (const float*)d_in[23];
    const float* v_w1    = (const float*)d_in[24];
    const float* v_b1    = (const float*)d_in[25];
    const float* v_w2    = (const float*)d_in[26];
    const float* v_b2    = (const float*)d_in[27];
    const float* fc2_w   = (const float*)d_in[28];
    const float* fc2_b   = (const float*)d_in[29];

    float* ws = (float*)d_ws;
    const size_t R = R_;
    // Workspace layout (floats); lifetimes managed by launch order:
    float* S0     = ws;               // R*384  (gi -> t1 -> t2 -> t3)
    float* S1     = S0 + R * 384;     // R*384  (gh -> tbn -> kv/qv)
    float* hbuf   = S1 + R * 384;     // R*128  (x, then h)
    float* lebuf  = hbuf + R * 128;   // R*128
    float* pmbuf  = lebuf + R * 128;  // R*64
    float* valbuf = pmbuf + R * 64;   // R*64
    float* khbuf  = valbuf + R * 64;  // R*32
    float* qhbuf  = khbuf + R * 32;   // R*32
    float* psum   = qhbuf + R * 32;   // 256*256
    float* psq    = psum + 256 * 256; // 256*256
    float* scale  = psq + 256 * 256;  // 256
    float* shift  = scale + 256;      // 256

    dim3 blk(256);
    dim3 g512(R_ / 64);

    // x = relu(fc1(inputs))        [R,128] (in h slot, dead before h written)
    gemm_k<128, 1><<<g512, blk, 0, stream>>>(inputs, 128, nullptr, fc1_w, fc1_b, hbuf, 128);
    // gi = x @ w_ih^T + b_ih       [R,384]
    gemm_k<128, 0><<<g512, blk, 0, stream>>>(hbuf, 128, nullptr, w_ih, b_ih, S0, 384);
    // gh = hidden @ w_hh^T + b_hh  [R,384]
    gemm_k<128, 0><<<g512, blk, 0, stream>>>(hidden, 128, nullptr, w_hh, b_hh, S1, 384);
    // GRU combine -> h             [R,128]
    gru_kernel<<<dim3(R_ * 128 / 256), blk, 0, stream>>>(S0, S1, hidden, hbuf);
    // lt = relu(lse1(latent))      [R,128]
    gemm_k<64, 1><<<g512, blk, 0, stream>>>(latent, 64, nullptr, lse_w1, lse_b1, S0, 128);
    // le = lse2(lt)                [R,128]
    gemm_k<128, 0><<<g512, blk, 0, stream>>>(S0, 128, nullptr, lse_w2, lse_b2, lebuf, 128);
    // t1 = me1(cat(h,le))          [R,256]
    gemm_k<256, 0><<<g512, blk, 0, stream>>>(hbuf, 128, lebuf, me_w1, me_b1, S0, 256);
    // BatchNorm stats (deterministic 2-stage)
    bn_stats_kernel<<<dim3(256), blk, 0, stream>>>(S0, psum, psq);
    bn_final_kernel<<<dim3(1), blk, 0, stream>>>(psum, psq, me_g, me_beta, scale, shift);
    // tbn = lrelu(bn(t1))          [R,256]
    bn_act_kernel<<<dim3(R_ * 256 / 256), blk, 0, stream>>>(S0, scale, shift, S1);
    // t2 = lrelu(me2(tbn))         [R,128]
    gemm_k<256, 2><<<g512, blk, 0, stream>>>(S1, 256, nullptr, me_w2, me_b2, S0, 128);
    // pm = clip(mean)+clip(std)*eps [R,64]
    pm_kernel<<<dim3(R_ * 64 / 256), blk, 0, stream>>>(S0, eps, pmbuf);
    // t3 = lrelu(v1(cat(h,pm)))    [R,256]
    gemm_k<192, 2><<<g512, blk, 0, stream>>>(hbuf, 128, pmbuf, v_w1, v_b1, S0, 256);
    // value = v2(t3)               [R,64]
    gemm_k<256, 0><<<g512, blk, 0, stream>>>(S0, 256, nullptr, v_w2, v_b2, valbuf, 64);
    // kv = k(h), qv = q(pm)        [R,32] each
    gemm_k<128, 0><<<g512, blk, 0, stream>>>(hbuf, 128, nullptr, k_w, k_b, S1, 32);
    gemm_k<64, 0><<<g512, blk, 0, stream>>>(pmbuf, 64, nullptr, q_w, q_b, S1 + R * 32, 32);
    // cosine-normalize rows
    norm_kernel<<<dim3(R_ * 32 / 256), blk, 0, stream>>>(S1, khbuf);
    norm_kernel<<<dim3(R_ * 32 / 256), blk, 0, stream>>>(S1 + R * 32, qhbuf);
    // attention + fc2 (msg folded via vproj)
    attn_out_kernel<<<dim3(BSB_), blk, 0, stream>>>(khbuf, qhbuf, valbuf, hbuf, lebuf,
                                                    fc2_w, fc2_b, (float*)d_out);
}

// Round 2
// 388.653 us; speedup vs baseline: 2.4984x; 2.4984x over previous
//
#include <hip/hip_runtime.h>
#include <math.h>

// Problem constants (fixed instance)
namespace {
constexpr int R_ = 32768;     // BS*N rows
constexpr int N_ = 16;
constexpr int NA_ = 30;
constexpr int BSB_ = R_ / N_; // 2048 batches
}

typedef __bf16 bf16x8 __attribute__((ext_vector_type(8)));
typedef float f32x4 __attribute__((ext_vector_type(4)));

__device__ inline unsigned int f2bf(float f) {
    unsigned int u = __float_as_uint(f);
    unsigned int r = (u + 0x7fffu + ((u >> 16) & 1u)) >> 16;  // RTN-even
    return r;
}
__device__ inline unsigned int pack2(float a, float b) {
    return f2bf(a) | (f2bf(b) << 16);
}
__device__ inline uint4 pack8(float4 f0, float4 f1) {
    uint4 u;
    u.x = pack2(f0.x, f0.y); u.y = pack2(f0.z, f0.w);
    u.z = pack2(f1.x, f1.y); u.w = pack2(f1.z, f1.w);
    return u;
}

// C[64 x O] = A[64 x K] * W[O x K]^T + bias, fused activation; bf16 MFMA engine.
// A may be a concat of A1 (width K1) and A2 (width K-K1); K1 multiple of 8.
// ACT: 0=none 1=relu 2=leakyrelu(0.01)
template<int K, int ACT>
__global__ __launch_bounds__(256)
void gemm_mfma(const float* __restrict__ A1, int K1,
               const float* __restrict__ A2,
               const float* __restrict__ W, const float* __restrict__ bias,
               float* __restrict__ out, int O)
{
    constexpr int KC = K / 8;              // 16B chunks per row
    __shared__ uint4 Atile[64 * KC];       // [row][K] bf16, XOR-swizzled 16B chunks
    __shared__ uint4 Btile[64 * 8];        // [orow][64] bf16 k-chunk, XOR-swizzled

    const int tid = threadIdx.x;
    const int r0 = blockIdx.x * 64;

    // ---- stage A (full K), fp32 -> bf16 RTN ----
    for (int idx = tid; idx < 64 * KC; idx += 256) {
        int row = idx / KC, c = idx - row * KC;
        int k = c * 8;
        const float4* p;
        if (k < K1) p = (const float4*)(A1 + (size_t)(r0 + row) * K1 + k);
        else        p = (const float4*)(A2 + (size_t)(r0 + row) * (K - K1) + (k - K1));
        Atile[(row * KC + c) ^ (row & 7)] = pack8(p[0], p[1]);
    }

    const int lane = tid & 63, w = tid >> 6;
    const int wr = w >> 1, wc = w & 1;
    const int m = lane & 15, g = lane >> 4;

    const int ntiles = (O + 63) >> 6;
    for (int ot = 0; ot < ntiles; ++ot) {
        const int o0 = ot * 64;
        f32x4 acc[2][2] = {};
        for (int kc64 = 0; kc64 < K / 64; ++kc64) {
            __syncthreads();  // Atile ready / previous Btile consumed
            // ---- stage B k-chunk: W[o0..o0+63][kc64*64 .. +63] ----
            for (int idx = tid; idx < 512; idx += 256) {
                int row = idx >> 3, c = idx & 7;
                int o = o0 + row;
                uint4 u;
                if (o < O) {
                    const float4* p = (const float4*)(W + (size_t)o * K + kc64 * 64 + c * 8);
                    u = pack8(p[0], p[1]);
                } else {
                    u = make_uint4(0, 0, 0, 0);
                }
                Btile[(row * 8 + c) ^ (row & 7)] = u;
            }
            __syncthreads();
            // ---- 2 MFMA k-steps of 32 over this 64-wide chunk ----
            #pragma unroll
            for (int kcl = 0; kcl < 2; ++kcl) {
                bf16x8 af[2], bfr[2];
                #pragma unroll
                for (int fr = 0; fr < 2; ++fr) {
                    int row = (wr * 2 + fr) * 16 + m;
                    int c = kc64 * 8 + kcl * 4 + g;
                    af[fr] = __builtin_bit_cast(bf16x8, Atile[(row * KC + c) ^ (row & 7)]);
                }
                #pragma unroll
                for (int fc = 0; fc < 2; ++fc) {
                    int row = (wc * 2 + fc) * 16 + m;
                    int c = kcl * 4 + g;
                    bfr[fc] = __builtin_bit_cast(bf16x8, Btile[(row * 8 + c) ^ (row & 7)]);
                }
                #pragma unroll
                for (int fr = 0; fr < 2; ++fr)
                    #pragma unroll
                    for (int fc = 0; fc < 2; ++fc)
                        acc[fr][fc] = __builtin_amdgcn_mfma_f32_16x16x32_bf16(
                            af[fr], bfr[fc], acc[fr][fc], 0, 0, 0);
            }
        }
        // ---- epilogue: bias + activation + store fp32 ----
        #pragma unroll
        for (int fc = 0; fc < 2; ++fc) {
            int col = o0 + (wc * 2 + fc) * 16 + m;
            if (col < O) {
                float bv = bias[col];
                #pragma unroll
                for (int fr = 0; fr < 2; ++fr) {
                    #pragma unroll
                    for (int i = 0; i < 4; ++i) {
                        int rowl = (wr * 2 + fr) * 16 + g * 4 + i;
                        float v = acc[fr][fc][i] + bv;
                        if (ACT == 1) v = v > 0.f ? v : 0.f;
                        if (ACT == 2) v = v > 0.f ? v : 0.01f * v;
                        out[(size_t)(r0 + rowl) * O + col] = v;
                    }
                }
            }
        }
    }
}

__global__ __launch_bounds__(256)
void gru_kernel(const float* __restrict__ gi, const float* __restrict__ gh,
                const float* __restrict__ hprev, float* __restrict__ h)
{
    int idx = blockIdx.x * 256 + threadIdx.x; // over R*128
    int r = idx >> 7, o = idx & 127;
    size_t base = (size_t)r * 384;
    float ir = gi[base + o], iz = gi[base + 128 + o], inn = gi[base + 256 + o];
    float hr = gh[base + o], hz = gh[base + 128 + o], hn = gh[base + 256 + o];
    float rg = 1.f / (1.f + expf(-(ir + hr)));
    float zg = 1.f / (1.f + expf(-(iz + hz)));
    float ng = tanhf(inn + rg * hn);
    float hp = hprev[idx];
    h[idx] = ng + zg * (hp - ng);
}

__global__ __launch_bounds__(256)
void bn_stats_kernel(const float* __restrict__ t1, float* __restrict__ psum, float* __restrict__ psq)
{
    int f = threadIdx.x;            // feature 0..255
    int rbase = blockIdx.x * (R_ / 256);
    float s = 0.f, ss = 0.f;
    for (int rr = 0; rr < R_ / 256; ++rr) {
        float v = t1[(size_t)(rbase + rr) * 256 + f];
        s += v; ss += v * v;
    }
    psum[blockIdx.x * 256 + f] = s;
    psq[blockIdx.x * 256 + f] = ss;
}

__global__ __launch_bounds__(256)
void bn_final_kernel(const float* __restrict__ psum, const float* __restrict__ psq,
                     const float* __restrict__ g, const float* __restrict__ beta,
                     float* __restrict__ scale, float* __restrict__ shift)
{
    int f = threadIdx.x;
    float s = 0.f, ss = 0.f;
    for (int b = 0; b < 256; ++b) { s += psum[b * 256 + f]; ss += psq[b * 256 + f]; }
    float mean = s / (float)R_;
    float var = ss / (float)R_ - mean * mean; // biased var (ddof=0)
    float istd = rsqrtf(var + 1e-5f);
    float sc = g[f] * istd;
    scale[f] = sc;
    shift[f] = beta[f] - mean * sc;
}

__global__ __launch_bounds__(256)
void bn_act_kernel(const float* __restrict__ t1, const float* __restrict__ scale,
                   const float* __restrict__ shift, float* __restrict__ outv)
{
    int idx = blockIdx.x * 256 + threadIdx.x; // over R*256
    int f = idx & 255;
    float v = t1[idx] * scale[f] + shift[f];
    outv[idx] = v > 0.f ? v : 0.01f * v;
}

__global__ __launch_bounds__(256)
void pm_kernel(const float* __restrict__ t2, const float* __restrict__ eps, float* __restrict__ pm)
{
    int idx = blockIdx.x * 256 + threadIdx.x; // over R*64
    int r = idx >> 6, c = idx & 63;
    float m = t2[(size_t)r * 128 + c];
    float s = t2[(size_t)r * 128 + 64 + c];
    m = fminf(fmaxf(m, -1.f), 1.f);
    s = fminf(fmaxf(s, 0.5f), 1.f);
    pm[idx] = m + s * eps[idx];
}

__global__ __launch_bounds__(256)
void norm_kernel(const float* __restrict__ in, float* __restrict__ outv)
{
    int idx = blockIdx.x * 256 + threadIdx.x; // over R*32, row width 32
    float v = in[idx];
    float ss = v * v;
    #pragma unroll
    for (int m = 16; m >= 1; m >>= 1) ss += __shfl_xor(ss, m); // reduce over 32-lane row group
    float n = sqrtf(ss);
    outv[idx] = v / fmaxf(n, 1e-8f);
}

__global__ __launch_bounds__(256)
void attn_out_kernel(const float* __restrict__ kh, const float* __restrict__ qh,
                     const float* __restrict__ value, const float* __restrict__ hS,
                     const float* __restrict__ le, const float* __restrict__ w2,
                     const float* __restrict__ b2, float* __restrict__ outv)
{
    __shared__ float kh_s[16][32], qh_s[16][32], al_s[16][16], vp_s[16][32];
    __shared__ float val_s[16][64], h_s[16][128], le_s[16][128];
    const int tid = threadIdx.x;
    const size_t rb = (size_t)blockIdx.x * 16;

    for (int idx = tid; idx < 512; idx += 256) {
        kh_s[idx >> 5][idx & 31] = kh[rb * 32 + idx];
        qh_s[idx >> 5][idx & 31] = qh[rb * 32 + idx];
    }
    for (int idx = tid; idx < 1024; idx += 256)
        val_s[idx >> 6][idx & 63] = value[rb * 64 + idx];
    for (int idx = tid; idx < 2048; idx += 256) {
        h_s[idx >> 7][idx & 127] = hS[rb * 128 + idx];
        le_s[idx >> 7][idx & 127] = le[rb * 128 + idx];
    }
    __syncthreads();

    { // logits + softmax over j (incl. diagonal), then zero diagonal
        int i = tid >> 4, j = tid & 15;
        float l = 0.f;
        #pragma unroll
        for (int a = 0; a < 32; ++a) l += kh_s[i][a] * qh_s[j][a];
        float mx = l;
        #pragma unroll
        for (int m = 8; m >= 1; m >>= 1) mx = fmaxf(mx, __shfl_xor(mx, m));
        float e = expf(l - mx);
        float s = e;
        #pragma unroll
        for (int m = 8; m >= 1; m >>= 1) s += __shfl_xor(s, m);
        float a = e / s;
        if (i == j) a = 0.f;
        al_s[i][j] = a;
    }
    __syncthreads();

    // vproj[j][na] = fc2_w[na, 256+64j : 256+64j+64] . value[j]
    for (int task = tid; task < 16 * NA_; task += 256) {
        int na = task >> 4, j = task & 15;
        const float4* wrow = (const float4*)&w2[(size_t)na * 1280 + 256 + j * 64];
        const float4* vrow = (const float4*)&val_s[j][0];
        float acc = 0.f;
        #pragma unroll
        for (int c = 0; c < 16; ++c) {
            float4 wv = wrow[c], vv = vrow[c];
            acc += wv.x * vv.x + wv.y * vv.y + wv.z * vv.z + wv.w * vv.w;
        }
        vp_s[j][na] = acc;
    }
    __syncthreads();

    // out[i][na] = b + fc2_hl . (h,le) + sum_j alpha[i][j]*vproj[j][na]
    for (int task = tid; task < 16 * NA_; task += 256) {
        int i = task / NA_, na = task - i * NA_;
        const float4* wrow = (const float4*)&w2[(size_t)na * 1280];
        const float4* hrow = (const float4*)&h_s[i][0];
        const float4* lerow = (const float4*)&le_s[i][0];
        float acc = b2[na];
        #pragma unroll 8
        for (int c = 0; c < 32; ++c) {
            float4 wv = wrow[c], hv = hrow[c];
            acc += wv.x * hv.x + wv.y * hv.y + wv.z * hv.z + wv.w * hv.w;
        }
        #pragma unroll 8
        for (int c = 0; c < 32; ++c) {
            float4 wv = wrow[32 + c], lv = lerow[c];
            acc += wv.x * lv.x + wv.y * lv.y + wv.z * lv.z + wv.w * lv.w;
        }
        #pragma unroll
        for (int j = 0; j < 16; ++j) acc += al_s[i][j] * vp_s[j][na];
        outv[(rb + i) * NA_ + na] = acc;
    }
}

extern "C" void kernel_launch(void* const* d_in, const int* in_sizes, int n_in,
                              void* d_out, int out_size, void* d_ws, size_t ws_size,
                              hipStream_t stream)
{
    (void)in_sizes; (void)n_in; (void)out_size; (void)ws_size;
    const float* inputs  = (const float*)d_in[0];
    const float* hidden  = (const float*)d_in[1];
    const float* latent  = (const float*)d_in[2];
    const float* eps     = (const float*)d_in[3];
    const float* fc1_w   = (const float*)d_in[4];
    const float* fc1_b   = (const float*)d_in[5];
    const float* w_ih    = (const float*)d_in[6];
    const float* w_hh    = (const float*)d_in[7];
    const float* b_ih    = (const float*)d_in[8];
    const float* b_hh    = (const float*)d_in[9];
    const float* lse_w1  = (const float*)d_in[10];
    const float* lse_b1  = (const float*)d_in[11];
    const float* lse_w2  = (const float*)d_in[12];
    const float* lse_b2  = (const float*)d_in[13];
    const float* me_w1   = (const float*)d_in[14];
    const float* me_b1   = (const float*)d_in[15];
    const float* me_g    = (const float*)d_in[16];
    const float* me_beta = (const float*)d_in[17];
    const float* me_w2   = (const float*)d_in[18];
    const float* me_b2   = (const float*)d_in[19];
    const float* k_w     = (const float*)d_in[20];
    const float* k_b     = (const float*)d_in[21];
    const float* q_w     = (const float*)d_in[22];
    const float* q_b     = (const float*)d_in[23];
    const float* v_w1    = (const float*)d_in[24];
    const float* v_b1    = (const float*)d_in[25];
    const float* v_w2    = (const float*)d_in[26];
    const float* v_b2    = (const float*)d_in[27];
    const float* fc2_w   = (const float*)d_in[28];
    const float* fc2_b   = (const float*)d_in[29];

    float* ws = (float*)d_ws;
    const size_t R = R_;
    // Workspace layout (floats); lifetimes managed by launch order:
    float* S0     = ws;               // R*384  (gi -> t1 -> t2 -> t3)
    float* S1     = S0 + R * 384;     // R*384  (gh -> tbn -> kv/qv)
    float* hbuf   = S1 + R * 384;     // R*128  (x, then h)
    float* lebuf  = hbuf + R * 128;   // R*128
    float* pmbuf  = lebuf + R * 128;  // R*64
    float* valbuf = pmbuf + R * 64;   // R*64
    float* khbuf  = valbuf + R * 64;  // R*32
    float* qhbuf  = khbuf + R * 32;   // R*32
    float* psum   = qhbuf + R * 32;   // 256*256
    float* psq    = psum + 256 * 256; // 256*256
    float* scale  = psq + 256 * 256;  // 256
    float* shift  = scale + 256;      // 256

    dim3 blk(256);
    dim3 g512(R_ / 64);

    // x = relu(fc1(inputs))        [R,128] (in h slot, dead before h written)
    gemm_mfma<128, 1><<<g512, blk, 0, stream>>>(inputs, 128, inputs, fc1_w, fc1_b, hbuf, 128);
    // gi = x @ w_ih^T + b_ih       [R,384]
    gemm_mfma<128, 0><<<g512, blk, 0, stream>>>(hbuf, 128, hbuf, w_ih, b_ih, S0, 384);
    // gh = hidden @ w_hh^T + b_hh  [R,384]
    gemm_mfma<128, 0><<<g512, blk, 0, stream>>>(hidden, 128, hidden, w_hh, b_hh, S1, 384);
    // GRU combine -> h             [R,128]
    gru_kernel<<<dim3(R_ * 128 / 256), blk, 0, stream>>>(S0, S1, hidden, hbuf);
    // lt = relu(lse1(latent))      [R,128]
    gemm_mfma<64, 1><<<g512, blk, 0, stream>>>(latent, 64, latent, lse_w1, lse_b1, S0, 128);
    // le = lse2(lt)                [R,128]
    gemm_mfma<128, 0><<<g512, blk, 0, stream>>>(S0, 128, S0, lse_w2, lse_b2, lebuf, 128);
    // t1 = me1(cat(h,le))          [R,256]
    gemm_mfma<256, 0><<<g512, blk, 0, stream>>>(hbuf, 128, lebuf, me_w1, me_b1, S0, 256);
    // BatchNorm stats (deterministic 2-stage)
    bn_stats_kernel<<<dim3(256), blk, 0, stream>>>(S0, psum, psq);
    bn_final_kernel<<<dim3(1), blk, 0, stream>>>(psum, psq, me_g, me_beta, scale, shift);
    // tbn = lrelu(bn(t1))          [R,256]
    bn_act_kernel<<<dim3(R_ * 256 / 256), blk, 0, stream>>>(S0, scale, shift, S1);
    // t2 = lrelu(me2(tbn))         [R,128]
    gemm_mfma<256, 2><<<g512, blk, 0, stream>>>(S1, 256, S1, me_w2, me_b2, S0, 128);
    // pm = clip(mean)+clip(std)*eps [R,64]
    pm_kernel<<<dim3(R_ * 64 / 256), blk, 0, stream>>>(S0, eps, pmbuf);
    // t3 = lrelu(v1(cat(h,pm)))    [R,256]
    gemm_mfma<192, 2><<<g512, blk, 0, stream>>>(hbuf, 128, pmbuf, v_w1, v_b1, S0, 256);
    // value = v2(t3)               [R,64]
    gemm_mfma<256, 0><<<g512, blk, 0, stream>>>(S0, 256, S0, v_w2, v_b2, valbuf, 64);
    // kv = k(h), qv = q(pm)        [R,32] each
    gemm_mfma<128, 0><<<g512, blk, 0, stream>>>(hbuf, 128, hbuf, k_w, k_b, S1, 32);
    gemm_mfma<64, 0><<<g512, blk, 0, stream>>>(pmbuf, 64, pmbuf, q_w, q_b, S1 + R * 32, 32);
    // cosine-normalize rows
    norm_kernel<<<dim3(R_ * 32 / 256), blk, 0, stream>>>(S1, khbuf);
    norm_kernel<<<dim3(R_ * 32 / 256), blk, 0, stream>>>(S1 + R * 32, qhbuf);
    // attention + fc2 (msg folded via vproj)
    attn_out_kernel<<<dim3(BSB_), blk, 0, stream>>>(khbuf, qhbuf, valbuf, hbuf, lebuf,
                                                    fc2_w, fc2_b, (float*)d_out);
}

// Round 3
// 277.174 us; speedup vs baseline: 3.5033x; 1.4022x over previous
//
#include <hip/hip_runtime.h>
#include <math.h>

// Problem constants (fixed instance)
namespace {
constexpr int R_ = 32768;     // BS*N rows
constexpr int N_ = 16;
constexpr int NA_ = 30;
constexpr int BSB_ = R_ / N_; // 2048 batches
}

typedef __bf16 bf16x8 __attribute__((ext_vector_type(8)));
typedef float f32x4 __attribute__((ext_vector_type(4)));

__device__ inline unsigned int f2bf(float f) {
    unsigned int u = __float_as_uint(f);
    unsigned int r = (u + 0x7fffu + ((u >> 16) & 1u)) >> 16;  // RTN-even
    return r;
}
__device__ inline unsigned int pack2(float a, float b) {
    return f2bf(a) | (f2bf(b) << 16);
}
__device__ inline uint4 pack8(float4 f0, float4 f1) {
    uint4 u;
    u.x = pack2(f0.x, f0.y); u.y = pack2(f0.z, f0.w);
    u.z = pack2(f1.x, f1.y); u.w = pack2(f1.z, f1.w);
    return u;
}

// C[64 x O] = A[64 x K] * W[O x K]^T + bias, fused activation; bf16 MFMA engine.
// A may be a concat of A1 (width K1) and A2 (width K-K1); K1 multiple of 8.
// W rows have stride wstride (>= K) to allow projecting a column-slice of a
// wider weight matrix. ACT: 0=none 1=relu 2=leakyrelu(0.01)
template<int K, int ACT>
__global__ __launch_bounds__(256)
void gemm_mfma(const float* __restrict__ A1, int K1,
               const float* __restrict__ A2,
               const float* __restrict__ W, int wstride,
               const float* __restrict__ bias,
               float* __restrict__ out, int O)
{
    constexpr int KC = K / 8;              // 16B chunks per row
    __shared__ uint4 Atile[64 * KC];       // [row][K] bf16, XOR-swizzled 16B chunks
    __shared__ uint4 Btile[64 * 8];        // [orow][64] bf16 k-chunk, XOR-swizzled

    const int tid = threadIdx.x;
    const int r0 = blockIdx.x * 64;

    // ---- stage A (full K), fp32 -> bf16 RTN ----
    for (int idx = tid; idx < 64 * KC; idx += 256) {
        int row = idx / KC, c = idx - row * KC;
        int k = c * 8;
        const float4* p;
        if (k < K1) p = (const float4*)(A1 + (size_t)(r0 + row) * K1 + k);
        else        p = (const float4*)(A2 + (size_t)(r0 + row) * (K - K1) + (k - K1));
        Atile[(row * KC + c) ^ (row & 7)] = pack8(p[0], p[1]);
    }

    const int lane = tid & 63, w = tid >> 6;
    const int wr = w >> 1, wc = w & 1;
    const int m = lane & 15, g = lane >> 4;

    const int ntiles = (O + 63) >> 6;
    for (int ot = 0; ot < ntiles; ++ot) {
        const int o0 = ot * 64;
        f32x4 acc[2][2] = {};
        for (int kc64 = 0; kc64 < K / 64; ++kc64) {
            __syncthreads();  // Atile ready / previous Btile consumed
            // ---- stage B k-chunk: W[o0..o0+63][kc64*64 .. +63] ----
            for (int idx = tid; idx < 512; idx += 256) {
                int row = idx >> 3, c = idx & 7;
                int o = o0 + row;
                uint4 u;
                if (o < O) {
                    const float4* p = (const float4*)(W + (size_t)o * wstride + kc64 * 64 + c * 8);
                    u = pack8(p[0], p[1]);
                } else {
                    u = make_uint4(0, 0, 0, 0);
                }
                Btile[(row * 8 + c) ^ (row & 7)] = u;
            }
            __syncthreads();
            // ---- 2 MFMA k-steps of 32 over this 64-wide chunk ----
            #pragma unroll
            for (int kcl = 0; kcl < 2; ++kcl) {
                bf16x8 af[2], bfr[2];
                #pragma unroll
                for (int fr = 0; fr < 2; ++fr) {
                    int row = (wr * 2 + fr) * 16 + m;
                    int c = kc64 * 8 + kcl * 4 + g;
                    af[fr] = __builtin_bit_cast(bf16x8, Atile[(row * KC + c) ^ (row & 7)]);
                }
                #pragma unroll
                for (int fc = 0; fc < 2; ++fc) {
                    int row = (wc * 2 + fc) * 16 + m;
                    int c = kcl * 4 + g;
                    bfr[fc] = __builtin_bit_cast(bf16x8, Btile[(row * 8 + c) ^ (row & 7)]);
                }
                #pragma unroll
                for (int fr = 0; fr < 2; ++fr)
                    #pragma unroll
                    for (int fc = 0; fc < 2; ++fc)
                        acc[fr][fc] = __builtin_amdgcn_mfma_f32_16x16x32_bf16(
                            af[fr], bfr[fc], acc[fr][fc], 0, 0, 0);
            }
        }
        // ---- epilogue: bias + activation + store fp32 ----
        #pragma unroll
        for (int fc = 0; fc < 2; ++fc) {
            int col = o0 + (wc * 2 + fc) * 16 + m;
            if (col < O) {
                float bv = bias[col];
                #pragma unroll
                for (int fr = 0; fr < 2; ++fr) {
                    #pragma unroll
                    for (int i = 0; i < 4; ++i) {
                        int rowl = (wr * 2 + fr) * 16 + g * 4 + i;
                        float v = acc[fr][fc][i] + bv;
                        if (ACT == 1) v = v > 0.f ? v : 0.f;
                        if (ACT == 2) v = v > 0.f ? v : 0.01f * v;
                        out[(size_t)(r0 + rowl) * O + col] = v;
                    }
                }
            }
        }
    }
}

__global__ __launch_bounds__(256)
void gru_kernel(const float* __restrict__ gi, const float* __restrict__ gh,
                const float* __restrict__ hprev, float* __restrict__ h)
{
    int idx = blockIdx.x * 256 + threadIdx.x; // over R*128
    int r = idx >> 7, o = idx & 127;
    size_t base = (size_t)r * 384;
    float ir = gi[base + o], iz = gi[base + 128 + o], inn = gi[base + 256 + o];
    float hr = gh[base + o], hz = gh[base + 128 + o], hn = gh[base + 256 + o];
    float rg = 1.f / (1.f + expf(-(ir + hr)));
    float zg = 1.f / (1.f + expf(-(iz + hz)));
    float ng = tanhf(inn + rg * hn);
    float hp = hprev[idx];
    h[idx] = ng + zg * (hp - ng);
}

__global__ __launch_bounds__(256)
void bn_stats_kernel(const float* __restrict__ t1, float* __restrict__ psum, float* __restrict__ psq)
{
    int f = threadIdx.x;            // feature 0..255
    int rbase = blockIdx.x * (R_ / 256);
    float s = 0.f, ss = 0.f;
    for (int rr = 0; rr < R_ / 256; ++rr) {
        float v = t1[(size_t)(rbase + rr) * 256 + f];
        s += v; ss += v * v;
    }
    psum[blockIdx.x * 256 + f] = s;
    psq[blockIdx.x * 256 + f] = ss;
}

__global__ __launch_bounds__(256)
void bn_final_kernel(const float* __restrict__ psum, const float* __restrict__ psq,
                     const float* __restrict__ g, const float* __restrict__ beta,
                     float* __restrict__ scale, float* __restrict__ shift)
{
    int f = threadIdx.x;
    float s = 0.f, ss = 0.f;
    for (int b = 0; b < 256; ++b) { s += psum[b * 256 + f]; ss += psq[b * 256 + f]; }
    float mean = s / (float)R_;
    float var = ss / (float)R_ - mean * mean; // biased var (ddof=0)
    float istd = rsqrtf(var + 1e-5f);
    float sc = g[f] * istd;
    scale[f] = sc;
    shift[f] = beta[f] - mean * sc;
}

__global__ __launch_bounds__(256)
void bn_act_kernel(const float* __restrict__ t1, const float* __restrict__ scale,
                   const float* __restrict__ shift, float* __restrict__ outv)
{
    int idx = blockIdx.x * 256 + threadIdx.x; // over R*256
    int f = idx & 255;
    float v = t1[idx] * scale[f] + shift[f];
    outv[idx] = v > 0.f ? v : 0.01f * v;
}

__global__ __launch_bounds__(256)
void pm_kernel(const float* __restrict__ t2, const float* __restrict__ eps, float* __restrict__ pm)
{
    int idx = blockIdx.x * 256 + threadIdx.x; // over R*64
    int r = idx >> 6, c = idx & 63;
    float m = t2[(size_t)r * 128 + c];
    float s = t2[(size_t)r * 128 + 64 + c];
    m = fminf(fmaxf(m, -1.f), 1.f);
    s = fminf(fmaxf(s, 0.5f), 1.f);
    pm[idx] = m + s * eps[idx];
}

__global__ __launch_bounds__(256)
void norm_kernel(const float* __restrict__ in, float* __restrict__ outv)
{
    int idx = blockIdx.x * 256 + threadIdx.x; // over R*32, row width 32
    float v = in[idx];
    float ss = v * v;
    #pragma unroll
    for (int m = 16; m >= 1; m >>= 1) ss += __shfl_xor(ss, m); // reduce over 32-lane row group
    float n = sqrtf(ss);
    outv[idx] = v / fmaxf(n, 1e-8f);
}

// vproj[r][na] = w2[na, 256 + 64*(r%16) .. +64] . value[r]
// One block: agent j = blockIdx.x & 15, 64 batches = blockIdx.x >> 4.
__global__ __launch_bounds__(256)
void vproj_kernel(const float* __restrict__ value, const float* __restrict__ w2,
                  float* __restrict__ vproj)
{
    __shared__ float w2s[NA_][65];   // stride 65: bank=(na+k)%32, conflict-free
    __shared__ float val_s[64][65];
    const int tid = threadIdx.x;
    const int j = blockIdx.x & 15;
    const int b0 = (blockIdx.x >> 4) * 64;

    for (int idx = tid; idx < NA_ * 64; idx += 256) {
        int na = idx >> 6, k = idx & 63;
        w2s[na][k] = w2[(size_t)na * 1280 + 256 + j * 64 + k];
    }
    for (int idx = tid; idx < 64 * 64; idx += 256) {
        int bl = idx >> 6, k = idx & 63;
        val_s[bl][k] = value[((size_t)(b0 + bl) * 16 + j) * 64 + k];
    }
    __syncthreads();

    for (int task = tid; task < 64 * NA_; task += 256) {
        int bl = task / NA_, na = task - bl * NA_;
        float acc = 0.f;
        #pragma unroll 16
        for (int k = 0; k < 64; ++k) acc = fmaf(val_s[bl][k], w2s[na][k], acc);
        vproj[((size_t)(b0 + bl) * 16 + j) * NA_ + na] = acc;
    }
}

// Per batch: cosine logits (16x16), softmax over j, zero diagonal,
// out[i] = hl[i] + sum_j alpha[i][j] * vproj[j]
__global__ __launch_bounds__(256)
void attn_combine(const float* __restrict__ kh, const float* __restrict__ qh,
                  const float* __restrict__ vproj, const float* __restrict__ hl,
                  float* __restrict__ outv)
{
    __shared__ float kh_s[16][33], qh_s[16][33];  // stride 33: conflict-free row reads
    __shared__ float al_s[16][16];
    __shared__ float vp_s[16][NA_];
    const int tid = threadIdx.x;
    const size_t rb = (size_t)blockIdx.x * 16;

    for (int idx = tid; idx < 512; idx += 256) {
        int r = idx >> 5, a = idx & 31;
        kh_s[r][a] = kh[rb * 32 + idx];
        qh_s[r][a] = qh[rb * 32 + idx];
    }
    for (int idx = tid; idx < 16 * NA_; idx += 256)
        vp_s[idx / NA_][idx % NA_] = vproj[rb * NA_ + idx];
    __syncthreads();

    { // logits + softmax over j (incl. diagonal), then zero diagonal
        int i = tid >> 4, j = tid & 15;
        float l = 0.f;
        #pragma unroll
        for (int a = 0; a < 32; ++a) l = fmaf(kh_s[i][a], qh_s[j][a], l);
        float mx = l;
        #pragma unroll
        for (int m = 8; m >= 1; m >>= 1) mx = fmaxf(mx, __shfl_xor(mx, m));
        float e = expf(l - mx);
        float s = e;
        #pragma unroll
        for (int m = 8; m >= 1; m >>= 1) s += __shfl_xor(s, m);
        float a = e / s;
        if (i == j) a = 0.f;
        al_s[i][j] = a;
    }
    __syncthreads();

    for (int task = tid; task < 16 * NA_; task += 256) {
        int i = task / NA_, na = task - i * NA_;
        float acc = hl[(rb + i) * NA_ + na];
        #pragma unroll
        for (int j = 0; j < 16; ++j) acc = fmaf(al_s[i][j], vp_s[j][na], acc);
        outv[(rb + i) * NA_ + na] = acc;
    }
}

extern "C" void kernel_launch(void* const* d_in, const int* in_sizes, int n_in,
                              void* d_out, int out_size, void* d_ws, size_t ws_size,
                              hipStream_t stream)
{
    (void)in_sizes; (void)n_in; (void)out_size; (void)ws_size;
    const float* inputs  = (const float*)d_in[0];
    const float* hidden  = (const float*)d_in[1];
    const float* latent  = (const float*)d_in[2];
    const float* eps     = (const float*)d_in[3];
    const float* fc1_w   = (const float*)d_in[4];
    const float* fc1_b   = (const float*)d_in[5];
    const float* w_ih    = (const float*)d_in[6];
    const float* w_hh    = (const float*)d_in[7];
    const float* b_ih    = (const float*)d_in[8];
    const float* b_hh    = (const float*)d_in[9];
    const float* lse_w1  = (const float*)d_in[10];
    const float* lse_b1  = (const float*)d_in[11];
    const float* lse_w2  = (const float*)d_in[12];
    const float* lse_b2  = (const float*)d_in[13];
    const float* me_w1   = (const float*)d_in[14];
    const float* me_b1   = (const float*)d_in[15];
    const float* me_g    = (const float*)d_in[16];
    const float* me_beta = (const float*)d_in[17];
    const float* me_w2   = (const float*)d_in[18];
    const float* me_b2   = (const float*)d_in[19];
    const float* k_w     = (const float*)d_in[20];
    const float* k_b     = (const float*)d_in[21];
    const float* q_w     = (const float*)d_in[22];
    const float* q_b     = (const float*)d_in[23];
    const float* v_w1    = (const float*)d_in[24];
    const float* v_b1    = (const float*)d_in[25];
    const float* v_w2    = (const float*)d_in[26];
    const float* v_b2    = (const float*)d_in[27];
    const float* fc2_w   = (const float*)d_in[28];
    const float* fc2_b   = (const float*)d_in[29];

    float* ws = (float*)d_ws;
    const size_t R = R_;
    // Workspace layout (floats); lifetimes managed by launch order:
    float* S0     = ws;               // R*384  (gi -> t1 -> t2 -> t3 -> hl/vproj)
    float* S1     = S0 + R * 384;     // R*384  (gh -> tbn -> kv/qv)
    float* hbuf   = S1 + R * 384;     // R*128  (x, then h)
    float* lebuf  = hbuf + R * 128;   // R*128
    float* pmbuf  = lebuf + R * 128;  // R*64
    float* valbuf = pmbuf + R * 64;   // R*64
    float* khbuf  = valbuf + R * 64;  // R*32
    float* qhbuf  = khbuf + R * 32;   // R*32
    float* psum   = qhbuf + R * 32;   // 256*256
    float* psq    = psum + 256 * 256; // 256*256
    float* scale  = psq + 256 * 256;  // 256
    float* shift  = scale + 256;      // 256
    float* hlbuf  = S0;               // R*30 (after S0's t3 is dead)
    float* vpbuf  = S0 + R * 32;      // R*30

    dim3 blk(256);
    dim3 g512(R_ / 64);

    // x = relu(fc1(inputs))        [R,128] (in h slot, dead before h written)
    gemm_mfma<128, 1><<<g512, blk, 0, stream>>>(inputs, 128, inputs, fc1_w, 128, fc1_b, hbuf, 128);
    // gi = x @ w_ih^T + b_ih       [R,384]
    gemm_mfma<128, 0><<<g512, blk, 0, stream>>>(hbuf, 128, hbuf, w_ih, 128, b_ih, S0, 384);
    // gh = hidden @ w_hh^T + b_hh  [R,384]
    gemm_mfma<128, 0><<<g512, blk, 0, stream>>>(hidden, 128, hidden, w_hh, 128, b_hh, S1, 384);
    // GRU combine -> h             [R,128]
    gru_kernel<<<dim3(R_ * 128 / 256), blk, 0, stream>>>(S0, S1, hidden, hbuf);
    // lt = relu(lse1(latent))      [R,128]
    gemm_mfma<64, 1><<<g512, blk, 0, stream>>>(latent, 64, latent, lse_w1, 64, lse_b1, S0, 128);
    // le = lse2(lt)                [R,128]
    gemm_mfma<128, 0><<<g512, blk, 0, stream>>>(S0, 128, S0, lse_w2, 128, lse_b2, lebuf, 128);
    // t1 = me1(cat(h,le))          [R,256]
    gemm_mfma<256, 0><<<g512, blk, 0, stream>>>(hbuf, 128, lebuf, me_w1, 256, me_b1, S0, 256);
    // BatchNorm stats (deterministic 2-stage)
    bn_stats_kernel<<<dim3(256), blk, 0, stream>>>(S0, psum, psq);
    bn_final_kernel<<<dim3(1), blk, 0, stream>>>(psum, psq, me_g, me_beta, scale, shift);
    // tbn = lrelu(bn(t1))          [R,256]
    bn_act_kernel<<<dim3(R_ * 256 / 256), blk, 0, stream>>>(S0, scale, shift, S1);
    // t2 = lrelu(me2(tbn))         [R,128]
    gemm_mfma<256, 2><<<g512, blk, 0, stream>>>(S1, 256, S1, me_w2, 256, me_b2, S0, 128);
    // pm = clip(mean)+clip(std)*eps [R,64]
    pm_kernel<<<dim3(R_ * 64 / 256), blk, 0, stream>>>(S0, eps, pmbuf);
    // t3 = lrelu(v1(cat(h,pm)))    [R,256]
    gemm_mfma<192, 2><<<g512, blk, 0, stream>>>(hbuf, 128, pmbuf, v_w1, 192, v_b1, S0, 256);
    // value = v2(t3)               [R,64]
    gemm_mfma<256, 0><<<g512, blk, 0, stream>>>(S0, 256, S0, v_w2, 256, v_b2, valbuf, 64);
    // kv = k(h), qv = q(pm)        [R,32] each
    gemm_mfma<128, 0><<<g512, blk, 0, stream>>>(hbuf, 128, hbuf, k_w, 128, k_b, S1, 32);
    gemm_mfma<64, 0><<<g512, blk, 0, stream>>>(pmbuf, 64, pmbuf, q_w, 64, q_b, S1 + R * 32, 32);
    // cosine-normalize rows
    norm_kernel<<<dim3(R_ * 32 / 256), blk, 0, stream>>>(S1, khbuf);
    norm_kernel<<<dim3(R_ * 32 / 256), blk, 0, stream>>>(S1 + R * 32, qhbuf);
    // hl = fc2_w[:, :256] . (h ‖ le) + fc2_b   [R,30]   (S0 free after v2)
    gemm_mfma<256, 0><<<g512, blk, 0, stream>>>(hbuf, 128, lebuf, fc2_w, 1280, fc2_b, hlbuf, NA_);
    // vproj = per-agent slice of fc2_w . value [R,30]
    vproj_kernel<<<dim3(16 * (BSB_ / 64)), blk, 0, stream>>>(valbuf, fc2_w, vpbuf);
    // attention combine -> out
    attn_combine<<<dim3(BSB_), blk, 0, stream>>>(khbuf, qhbuf, vpbuf, hlbuf, (float*)d_out);
}

// Round 4
// 200.759 us; speedup vs baseline: 4.8367x; 1.3806x over previous
//
#include <hip/hip_runtime.h>
#include <math.h>

// Problem constants (fixed instance)
namespace {
constexpr int R_ = 32768;     // BS*N rows
constexpr int N_ = 16;
constexpr int NA_ = 30;
constexpr int BSB_ = R_ / N_; // 2048 batches
}

typedef __bf16 bf16x8 __attribute__((ext_vector_type(8)));
typedef float f32x4 __attribute__((ext_vector_type(4)));

__device__ inline unsigned int f2bf(float f) {
    unsigned int u = __float_as_uint(f);
    return (u + 0x7fffu + ((u >> 16) & 1u)) >> 16;  // RTN-even
}
__device__ inline float bf2f(unsigned int us) {
    return __uint_as_float(us << 16);
}
__device__ inline unsigned int pack2(float a, float b) {
    return f2bf(a) | (f2bf(b) << 16);
}
__device__ inline uint4 pack8(float4 f0, float4 f1) {
    uint4 u;
    u.x = pack2(f0.x, f0.y); u.y = pack2(f0.z, f0.w);
    u.z = pack2(f1.x, f1.y); u.w = pack2(f1.z, f1.w);
    return u;
}
__device__ inline float sigmoidf_(float x) { return 1.f / (1.f + expf(-x)); }

// ---------------------------------------------------------------------------
// Generic bf16-MFMA GEMM: C[64 x O] = A[64 x K] * W[O x K]^T + bias (+act).
// A = concat(A1 width K1, A2 width K-K1). ABF: A buffers are bf16. OBF: store bf16.
// ACT: 0=none 1=relu 2=leakyrelu(0.01)
template<int K, int ACT, bool ABF, bool OBF>
__global__ __launch_bounds__(256, 2)
void gemm_mfma(const void* __restrict__ A1v, int K1,
               const void* __restrict__ A2v,
               const float* __restrict__ W, int wstride,
               const float* __restrict__ bias,
               void* __restrict__ outv, int O)
{
    constexpr int KC = K / 8;              // 16B chunks per row
    __shared__ uint4 Atile[64 * KC];       // bf16, XOR-swizzled 16B chunks
    __shared__ uint4 Btile[64 * 8];

    const int tid = threadIdx.x;
    const int r0 = blockIdx.x * 64;

    for (int idx = tid; idx < 64 * KC; idx += 256) {
        int row = idx / KC, c = idx - row * KC;
        int k = c * 8;
        uint4 u;
        if (ABF) {
            const unsigned short* src;
            if (k < K1) src = (const unsigned short*)A1v + (size_t)(r0 + row) * K1 + k;
            else        src = (const unsigned short*)A2v + (size_t)(r0 + row) * (K - K1) + (k - K1);
            u = *(const uint4*)src;
        } else {
            const float* src;
            if (k < K1) src = (const float*)A1v + (size_t)(r0 + row) * K1 + k;
            else        src = (const float*)A2v + (size_t)(r0 + row) * (K - K1) + (k - K1);
            const float4* p = (const float4*)src;
            u = pack8(p[0], p[1]);
        }
        Atile[(row * KC + c) ^ (row & 7)] = u;
    }

    const int lane = tid & 63, w = tid >> 6;
    const int wr = w >> 1, wc = w & 1;
    const int m = lane & 15, g = lane >> 4;

    const int ntiles = (O + 63) >> 6;
    for (int ot = 0; ot < ntiles; ++ot) {
        const int o0 = ot * 64;
        f32x4 acc[2][2] = {};
        for (int kc64 = 0; kc64 < K / 64; ++kc64) {
            __syncthreads();
            for (int idx = tid; idx < 512; idx += 256) {
                int row = idx >> 3, c = idx & 7;
                int o = o0 + row;
                uint4 u = make_uint4(0, 0, 0, 0);
                if (o < O) {
                    const float4* p = (const float4*)(W + (size_t)o * wstride + kc64 * 64 + c * 8);
                    u = pack8(p[0], p[1]);
                }
                Btile[(row * 8 + c) ^ (row & 7)] = u;
            }
            __syncthreads();
            #pragma unroll
            for (int kcl = 0; kcl < 2; ++kcl) {
                bf16x8 af[2], bfr[2];
                #pragma unroll
                for (int fr = 0; fr < 2; ++fr) {
                    int row = (wr * 2 + fr) * 16 + m;
                    int c = kc64 * 8 + kcl * 4 + g;
                    af[fr] = __builtin_bit_cast(bf16x8, Atile[(row * KC + c) ^ (row & 7)]);
                }
                #pragma unroll
                for (int fc = 0; fc < 2; ++fc) {
                    int row = (wc * 2 + fc) * 16 + m;
                    int c = kcl * 4 + g;
                    bfr[fc] = __builtin_bit_cast(bf16x8, Btile[(row * 8 + c) ^ (row & 7)]);
                }
                #pragma unroll
                for (int fr = 0; fr < 2; ++fr)
                    #pragma unroll
                    for (int fc = 0; fc < 2; ++fc)
                        acc[fr][fc] = __builtin_amdgcn_mfma_f32_16x16x32_bf16(
                            af[fr], bfr[fc], acc[fr][fc], 0, 0, 0);
            }
        }
        #pragma unroll
        for (int fc = 0; fc < 2; ++fc) {
            int col = o0 + (wc * 2 + fc) * 16 + m;
            if (col < O) {
                float bv = bias[col];
                #pragma unroll
                for (int fr = 0; fr < 2; ++fr) {
                    #pragma unroll
                    for (int i = 0; i < 4; ++i) {
                        int rowl = (wr * 2 + fr) * 16 + g * 4 + i;
                        float v = acc[fr][fc][i] + bv;
                        if (ACT == 1) v = v > 0.f ? v : 0.f;
                        if (ACT == 2) v = v > 0.f ? v : 0.01f * v;
                        size_t oi = (size_t)(r0 + rowl) * O + col;
                        if (OBF) ((unsigned short*)outv)[oi] = (unsigned short)f2bf(v);
                        else     ((float*)outv)[oi] = v;
                    }
                }
            }
        }
    }
}

// ---------------------------------------------------------------------------
// GRU fused GEMM: A=[x(bf16,128) | hidden(f32,128)], three accumulator sets:
//   rr = A . [w_ih_r | w_hh_r]^T  (= ir+hr),  zz likewise,
//   ni = x . w_ih_n^T,  nh = hidden . w_hh_n^T.
// Epilogue computes h = ng + z*(hprev-ng), stores bf16.
__global__ __launch_bounds__(256, 2)
void gru_gemm(const unsigned short* __restrict__ xb, const float* __restrict__ hidden,
              const float* __restrict__ w_ih, const float* __restrict__ w_hh,
              const float* __restrict__ b_ih, const float* __restrict__ b_hh,
              unsigned short* __restrict__ hb)
{
    __shared__ uint4 Atile[64 * 32];
    __shared__ uint4 Brr[64 * 8], Bzz[64 * 8], Bn[64 * 8];
    const int tid = threadIdx.x;
    const int r0 = blockIdx.x * 64;

    for (int idx = tid; idx < 64 * 32; idx += 256) {
        int row = idx >> 5, c = idx & 31;
        uint4 u;
        if (c < 16) {
            u = *(const uint4*)(xb + (size_t)(r0 + row) * 128 + c * 8);
        } else {
            const float4* p = (const float4*)(hidden + (size_t)(r0 + row) * 128 + (c - 16) * 8);
            u = pack8(p[0], p[1]);
        }
        Atile[(row * 32 + c) ^ (row & 7)] = u;
    }

    const int lane = tid & 63, w = tid >> 6;
    const int wr = w >> 1, wc = w & 1;
    const int m = lane & 15, g = lane >> 4;

    for (int ot = 0; ot < 2; ++ot) {
        const int o0 = ot * 64;
        f32x4 rr[2][2] = {}, zz[2][2] = {}, ni[2][2] = {}, nh[2][2] = {};
        for (int kc64 = 0; kc64 < 4; ++kc64) {
            __syncthreads();
            const float* Wsrc = (kc64 < 2) ? w_ih : w_hh;
            const int koff = (kc64 & 1) * 64;
            for (int idx = tid; idx < 512; idx += 256) {
                int row = idx >> 3, c = idx & 7;
                int o = o0 + row;
                int s = (row * 8 + c) ^ (row & 7);
                const float4* p;
                p = (const float4*)(Wsrc + (size_t)o * 128 + koff + c * 8);
                Brr[s] = pack8(p[0], p[1]);
                p = (const float4*)(Wsrc + (size_t)(128 + o) * 128 + koff + c * 8);
                Bzz[s] = pack8(p[0], p[1]);
                p = (const float4*)(Wsrc + (size_t)(256 + o) * 128 + koff + c * 8);
                Bn[s] = pack8(p[0], p[1]);
            }
            __syncthreads();
            #pragma unroll
            for (int kcl = 0; kcl < 2; ++kcl) {
                bf16x8 af[2], br_[2], bz_[2], bn_[2];
                #pragma unroll
                for (int fr = 0; fr < 2; ++fr) {
                    int row = (wr * 2 + fr) * 16 + m;
                    int c = kc64 * 8 + kcl * 4 + g;
                    af[fr] = __builtin_bit_cast(bf16x8, Atile[(row * 32 + c) ^ (row & 7)]);
                }
                #pragma unroll
                for (int fc = 0; fc < 2; ++fc) {
                    int row = (wc * 2 + fc) * 16 + m;
                    int c = kcl * 4 + g;
                    int s = (row * 8 + c) ^ (row & 7);
                    br_[fc] = __builtin_bit_cast(bf16x8, Brr[s]);
                    bz_[fc] = __builtin_bit_cast(bf16x8, Bzz[s]);
                    bn_[fc] = __builtin_bit_cast(bf16x8, Bn[s]);
                }
                #pragma unroll
                for (int fr = 0; fr < 2; ++fr)
                    #pragma unroll
                    for (int fc = 0; fc < 2; ++fc) {
                        rr[fr][fc] = __builtin_amdgcn_mfma_f32_16x16x32_bf16(af[fr], br_[fc], rr[fr][fc], 0, 0, 0);
                        zz[fr][fc] = __builtin_amdgcn_mfma_f32_16x16x32_bf16(af[fr], bz_[fc], zz[fr][fc], 0, 0, 0);
                        if (kc64 < 2)
                            ni[fr][fc] = __builtin_amdgcn_mfma_f32_16x16x32_bf16(af[fr], bn_[fc], ni[fr][fc], 0, 0, 0);
                        else
                            nh[fr][fc] = __builtin_amdgcn_mfma_f32_16x16x32_bf16(af[fr], bn_[fc], nh[fr][fc], 0, 0, 0);
                    }
            }
        }
        #pragma unroll
        for (int fc = 0; fc < 2; ++fc) {
            int c = o0 + (wc * 2 + fc) * 16 + m;  // gate col 0..127
            float brz = b_ih[c] + b_hh[c];
            float bzz = b_ih[128 + c] + b_hh[128 + c];
            float bin = b_ih[256 + c], bhn = b_hh[256 + c];
            #pragma unroll
            for (int fr = 0; fr < 2; ++fr) {
                #pragma unroll
                for (int i = 0; i < 4; ++i) {
                    int row = r0 + (wr * 2 + fr) * 16 + g * 4 + i;
                    float rv = sigmoidf_(rr[fr][fc][i] + brz);
                    float zv = sigmoidf_(zz[fr][fc][i] + bzz);
                    float ng = tanhf(ni[fr][fc][i] + bin + rv * (nh[fr][fc][i] + bhn));
                    float hp = hidden[(size_t)row * 128 + c];
                    float hv = ng + zv * (hp - ng);
                    hb[(size_t)row * 128 + c] = (unsigned short)f2bf(hv);
                }
            }
        }
    }
}

// ---------------------------------------------------------------------------
// me1 GEMM (K=256, O=256, A=[h|le] bf16) + per-block BN partial sums epilogue.
__global__ __launch_bounds__(256, 2)
void me1_stats(const unsigned short* __restrict__ hb, const unsigned short* __restrict__ leb,
               const float* __restrict__ W, const float* __restrict__ bias,
               unsigned short* __restrict__ t1,
               float* __restrict__ psum, float* __restrict__ psq)
{
    constexpr int KC = 32;
    __shared__ uint4 Atile[64 * KC];
    __shared__ uint4 Btile[64 * 8];
    __shared__ float sredS[2][2][2][16];  // [wr][wc][fc][m]
    __shared__ float sredQ[2][2][2][16];
    const int tid = threadIdx.x;
    const int r0 = blockIdx.x * 64;

    for (int idx = tid; idx < 64 * 32; idx += 256) {
        int row = idx >> 5, c = idx & 31;
        const unsigned short* src = (c < 16)
            ? hb + (size_t)(r0 + row) * 128 + c * 8
            : leb + (size_t)(r0 + row) * 128 + (c - 16) * 8;
        Atile[(row * 32 + c) ^ (row & 7)] = *(const uint4*)src;
    }

    const int lane = tid & 63, w = tid >> 6;
    const int wr = w >> 1, wc = w & 1;
    const int m = lane & 15, g = lane >> 4;

    for (int ot = 0; ot < 4; ++ot) {
        const int o0 = ot * 64;
        f32x4 acc[2][2] = {};
        for (int kc64 = 0; kc64 < 4; ++kc64) {
            __syncthreads();
            for (int idx = tid; idx < 512; idx += 256) {
                int row = idx >> 3, c = idx & 7;
                const float4* p = (const float4*)(W + (size_t)(o0 + row) * 256 + kc64 * 64 + c * 8);
                Btile[(row * 8 + c) ^ (row & 7)] = pack8(p[0], p[1]);
            }
            __syncthreads();
            #pragma unroll
            for (int kcl = 0; kcl < 2; ++kcl) {
                bf16x8 af[2], bfr[2];
                #pragma unroll
                for (int fr = 0; fr < 2; ++fr) {
                    int row = (wr * 2 + fr) * 16 + m;
                    int c = kc64 * 8 + kcl * 4 + g;
                    af[fr] = __builtin_bit_cast(bf16x8, Atile[(row * 32 + c) ^ (row & 7)]);
                }
                #pragma unroll
                for (int fc = 0; fc < 2; ++fc) {
                    int row = (wc * 2 + fc) * 16 + m;
                    int c = kcl * 4 + g;
                    bfr[fc] = __builtin_bit_cast(bf16x8, Btile[(row * 8 + c) ^ (row & 7)]);
                }
                #pragma unroll
                for (int fr = 0; fr < 2; ++fr)
                    #pragma unroll
                    for (int fc = 0; fc < 2; ++fc)
                        acc[fr][fc] = __builtin_amdgcn_mfma_f32_16x16x32_bf16(
                            af[fr], bfr[fc], acc[fr][fc], 0, 0, 0);
            }
        }
        #pragma unroll
        for (int fc = 0; fc < 2; ++fc) {
            int col = o0 + (wc * 2 + fc) * 16 + m;
            float bv = bias[col];
            float s = 0.f, q = 0.f;
            #pragma unroll
            for (int fr = 0; fr < 2; ++fr) {
                #pragma unroll
                for (int i = 0; i < 4; ++i) {
                    int rowl = (wr * 2 + fr) * 16 + g * 4 + i;
                    float v = acc[fr][fc][i] + bv;
                    t1[(size_t)(r0 + rowl) * 256 + col] = (unsigned short)f2bf(v);
                    s += v; q += v * v;
                }
            }
            s += __shfl_xor(s, 16); s += __shfl_xor(s, 32);  // over g
            q += __shfl_xor(q, 16); q += __shfl_xor(q, 32);
            if (lane < 16) { sredS[wr][wc][fc][m] = s; sredQ[wr][wc][fc][m] = q; }
        }
        __syncthreads();
        if (tid < 64) {
            int wcfc = tid >> 4, mm = tid & 15;
            int wc2 = wcfc >> 1, fc2 = wcfc & 1;
            psum[(size_t)blockIdx.x * 256 + o0 + tid] =
                sredS[0][wc2][fc2][mm] + sredS[1][wc2][fc2][mm];
            psq[(size_t)blockIdx.x * 256 + o0 + tid] =
                sredQ[0][wc2][fc2][mm] + sredQ[1][wc2][fc2][mm];
        }
        // next iteration's first __syncthreads protects sred reuse
    }
}

__global__ __launch_bounds__(256)
void bn_final_kernel(const float* __restrict__ psum, const float* __restrict__ psq,
                     const float* __restrict__ g, const float* __restrict__ beta,
                     float* __restrict__ scale, float* __restrict__ shift)
{
    int f = threadIdx.x;
    float s = 0.f, ss = 0.f;
    for (int b = 0; b < 512; ++b) { s += psum[(size_t)b * 256 + f]; ss += psq[(size_t)b * 256 + f]; }
    float mean = s / (float)R_;
    float var = ss / (float)R_ - mean * mean; // biased var
    float istd = rsqrtf(var + 1e-5f);
    float sc = g[f] * istd;
    scale[f] = sc;
    shift[f] = beta[f] - mean * sc;
}

// ---------------------------------------------------------------------------
// me2 GEMM with BN(scale/shift)+lrelu fused into A-staging (t1 bf16 input),
// epilogue computes pm = clip(mean,-1,1) + clip(std,.5,1)*eps, stores bf16.
__global__ __launch_bounds__(256, 2)
void me2pm(const unsigned short* __restrict__ t1,
           const float* __restrict__ scale, const float* __restrict__ shift,
           const float* __restrict__ W, const float* __restrict__ bias,
           const float* __restrict__ eps, unsigned short* __restrict__ pm)
{
    constexpr int KC = 32;
    __shared__ uint4 Atile[64 * KC];
    __shared__ uint4 Btile[64 * 8];
    __shared__ float sc_s[256], sh_s[256];
    const int tid = threadIdx.x;
    const int r0 = blockIdx.x * 64;

    sc_s[tid] = scale[tid];
    sh_s[tid] = shift[tid];
    __syncthreads();

    for (int idx = tid; idx < 64 * 32; idx += 256) {
        int row = idx >> 5, c = idx & 31;
        uint4 u = *(const uint4*)(t1 + (size_t)(r0 + row) * 256 + c * 8);
        unsigned int vv[4] = {u.x, u.y, u.z, u.w};
        float f[8];
        #pragma unroll
        for (int q2 = 0; q2 < 4; ++q2) {
            f[2 * q2]     = __uint_as_float((vv[q2] & 0xffffu) << 16);
            f[2 * q2 + 1] = __uint_as_float(vv[q2] & 0xffff0000u);
        }
        int k = c * 8;
        #pragma unroll
        for (int j = 0; j < 8; ++j) {
            float v = f[j] * sc_s[k + j] + sh_s[k + j];
            f[j] = v > 0.f ? v : 0.01f * v;
        }
        uint4 r;
        r.x = pack2(f[0], f[1]); r.y = pack2(f[2], f[3]);
        r.z = pack2(f[4], f[5]); r.w = pack2(f[6], f[7]);
        Atile[(row * 32 + c) ^ (row & 7)] = r;
    }

    const int lane = tid & 63, w = tid >> 6;
    const int wr = w >> 1, wc = w & 1;
    const int m = lane & 15, g = lane >> 4;

    float msave[2][2][4];  // clipped mean from ot=0: [fc][fr][i]
    for (int ot = 0; ot < 2; ++ot) {
        const int o0 = ot * 64;
        f32x4 acc[2][2] = {};
        for (int kc64 = 0; kc64 < 4; ++kc64) {
            __syncthreads();
            for (int idx = tid; idx < 512; idx += 256) {
                int row = idx >> 3, c = idx & 7;
                const float4* p = (const float4*)(W + (size_t)(o0 + row) * 256 + kc64 * 64 + c * 8);
                Btile[(row * 8 + c) ^ (row & 7)] = pack8(p[0], p[1]);
            }
            __syncthreads();
            #pragma unroll
            for (int kcl = 0; kcl < 2; ++kcl) {
                bf16x8 af[2], bfr[2];
                #pragma unroll
                for (int fr = 0; fr < 2; ++fr) {
                    int row = (wr * 2 + fr) * 16 + m;
                    int c = kc64 * 8 + kcl * 4 + g;
                    af[fr] = __builtin_bit_cast(bf16x8, Atile[(row * 32 + c) ^ (row & 7)]);
                }
                #pragma unroll
                for (int fc = 0; fc < 2; ++fc) {
                    int row = (wc * 2 + fc) * 16 + m;
                    int c = kcl * 4 + g;
                    bfr[fc] = __builtin_bit_cast(bf16x8, Btile[(row * 8 + c) ^ (row & 7)]);
                }
                #pragma unroll
                for (int fr = 0; fr < 2; ++fr)
                    #pragma unroll
                    for (int fc = 0; fc < 2; ++fc)
                        acc[fr][fc] = __builtin_amdgcn_mfma_f32_16x16x32_bf16(
                            af[fr], bfr[fc], acc[fr][fc], 0, 0, 0);
            }
        }
        #pragma unroll
        for (int fc = 0; fc < 2; ++fc) {
            int cp = (wc * 2 + fc) * 16 + m;  // 0..63
            float bv = bias[o0 + cp];
            #pragma unroll
            for (int fr = 0; fr < 2; ++fr) {
                #pragma unroll
                for (int i = 0; i < 4; ++i) {
                    float v = acc[fr][fc][i] + bv;
                    v = v > 0.f ? v : 0.01f * v;  // lrelu BEFORE clip
                    if (ot == 0) {
                        msave[fc][fr][i] = fminf(fmaxf(v, -1.f), 1.f);
                    } else {
                        float sd = fminf(fmaxf(v, 0.5f), 1.f);
                        int row = r0 + (wr * 2 + fr) * 16 + g * 4 + i;
                        float e = eps[(size_t)row * 64 + cp];
                        pm[(size_t)row * 64 + cp] =
                            (unsigned short)f2bf(msave[fc][fr][i] + sd * e);
                    }
                }
            }
        }
    }
}

// ---------------------------------------------------------------------------
// k(h) and q(pm) GEMMs + cosine row-normalization, fused. 4 waves:
// waves 0-1 -> kv rows [w*32, w*32+32); waves 2-3 -> qv rows likewise.
__global__ __launch_bounds__(256, 2)
void kq_norm(const unsigned short* __restrict__ hb, const unsigned short* __restrict__ pmb,
             const float* __restrict__ k_w, const float* __restrict__ k_b,
             const float* __restrict__ q_w, const float* __restrict__ q_b,
             float* __restrict__ kh, float* __restrict__ qh)
{
    __shared__ uint4 Ah[64 * 16];   // h 64x128 bf16
    __shared__ uint4 Apm[64 * 8];   // pm 64x64
    __shared__ uint4 Bk[32 * 16];   // k_w 32x128 bf16
    __shared__ uint4 Bq[32 * 8];    // q_w 32x64
    const int tid = threadIdx.x;
    const int r0 = blockIdx.x * 64;

    for (int idx = tid; idx < 64 * 16; idx += 256) {
        int row = idx >> 4, c = idx & 15;
        Ah[(row * 16 + c) ^ (row & 7)] = *(const uint4*)(hb + (size_t)(r0 + row) * 128 + c * 8);
    }
    for (int idx = tid; idx < 64 * 8; idx += 256) {
        int row = idx >> 3, c = idx & 7;
        Apm[(row * 8 + c) ^ (row & 7)] = *(const uint4*)(pmb + (size_t)(r0 + row) * 64 + c * 8);
    }
    for (int idx = tid; idx < 32 * 16; idx += 256) {
        int row = idx >> 4, c = idx & 15;
        const float4* p = (const float4*)(k_w + (size_t)row * 128 + c * 8);
        Bk[(row * 16 + c) ^ (row & 7)] = pack8(p[0], p[1]);
    }
    for (int idx = tid; idx < 32 * 8; idx += 256) {
        int row = idx >> 3, c = idx & 7;
        const float4* p = (const float4*)(q_w + (size_t)row * 64 + c * 8);
        Bq[(row * 8 + c) ^ (row & 7)] = pack8(p[0], p[1]);
    }
    __syncthreads();

    const int lane = tid & 63, w = tid >> 6;
    const int m = lane & 15, g = lane >> 4;
    const bool isq = w >= 2;
    const int half = w & 1;

    f32x4 acc[2][2] = {};
    const int nks = isq ? 2 : 4;
    for (int ks = 0; ks < nks; ++ks) {
        bf16x8 af[2], bfr[2];
        #pragma unroll
        for (int fr = 0; fr < 2; ++fr) {
            int row = half * 32 + fr * 16 + m;
            int c = ks * 4 + g;
            af[fr] = __builtin_bit_cast(bf16x8,
                isq ? Apm[(row * 8 + c) ^ (row & 7)] : Ah[(row * 16 + c) ^ (row & 7)]);
        }
        #pragma unroll
        for (int fc = 0; fc < 2; ++fc) {
            int row = fc * 16 + m;
            int c = ks * 4 + g;
            bfr[fc] = __builtin_bit_cast(bf16x8,
                isq ? Bq[(row * 8 + c) ^ (row & 7)] : Bk[(row * 16 + c) ^ (row & 7)]);
        }
        #pragma unroll
        for (int fr = 0; fr < 2; ++fr)
            #pragma unroll
            for (int fc = 0; fc < 2; ++fc)
                acc[fr][fc] = __builtin_amdgcn_mfma_f32_16x16x32_bf16(
                    af[fr], bfr[fc], acc[fr][fc], 0, 0, 0);
    }

    const float* bias = isq ? q_b : k_b;
    float b0 = bias[m], b1 = bias[16 + m];
    float* outp = isq ? qh : kh;
    #pragma unroll
    for (int fr = 0; fr < 2; ++fr) {
        #pragma unroll
        for (int i = 0; i < 4; ++i) {
            float v0 = acc[fr][0][i] + b0;
            float v1 = acc[fr][1][i] + b1;
            float ss = v0 * v0 + v1 * v1;
            ss += __shfl_xor(ss, 1); ss += __shfl_xor(ss, 2);
            ss += __shfl_xor(ss, 4); ss += __shfl_xor(ss, 8);
            float inv = 1.f / fmaxf(sqrtf(ss), 1e-8f);
            int row = r0 + half * 32 + fr * 16 + g * 4 + i;
            outp[(size_t)row * 32 + m] = v0 * inv;
            outp[(size_t)row * 32 + 16 + m] = v1 * inv;
        }
    }
}

// ---------------------------------------------------------------------------
// vproj[r][na] = w2[na, 256+64*(r%16) .. +64] . value[r]   (value bf16)
__global__ __launch_bounds__(256)
void vproj_kernel(const unsigned short* __restrict__ value, const float* __restrict__ w2,
                  float* __restrict__ vproj)
{
    __shared__ float w2s[NA_][65];
    __shared__ float val_s[64][65];
    const int tid = threadIdx.x;
    const int j = blockIdx.x & 15;
    const int b0 = (blockIdx.x >> 4) * 64;

    for (int idx = tid; idx < NA_ * 64; idx += 256) {
        int na = idx >> 6, k = idx & 63;
        w2s[na][k] = w2[(size_t)na * 1280 + 256 + j * 64 + k];
    }
    for (int idx = tid; idx < 64 * 64; idx += 256) {
        int bl = idx >> 6, k = idx & 63;
        val_s[bl][k] = bf2f(value[((size_t)(b0 + bl) * 16 + j) * 64 + k]);
    }
    __syncthreads();

    for (int task = tid; task < 64 * NA_; task += 256) {
        int bl = task / NA_, na = task - bl * NA_;
        float acc = 0.f;
        #pragma unroll 16
        for (int k = 0; k < 64; ++k) acc = fmaf(val_s[bl][k], w2s[na][k], acc);
        vproj[((size_t)(b0 + bl) * 16 + j) * NA_ + na] = acc;
    }
}

// Per batch: cosine logits (16x16), softmax over j, zero diag, combine.
__global__ __launch_bounds__(256)
void attn_combine(const float* __restrict__ kh, const float* __restrict__ qh,
                  const float* __restrict__ vproj, const float* __restrict__ hl,
                  float* __restrict__ outv)
{
    __shared__ float kh_s[16][33], qh_s[16][33];
    __shared__ float al_s[16][16];
    __shared__ float vp_s[16][NA_];
    const int tid = threadIdx.x;
    const size_t rb = (size_t)blockIdx.x * 16;

    for (int idx = tid; idx < 512; idx += 256) {
        int r = idx >> 5, a = idx & 31;
        kh_s[r][a] = kh[rb * 32 + idx];
        qh_s[r][a] = qh[rb * 32 + idx];
    }
    for (int idx = tid; idx < 16 * NA_; idx += 256)
        vp_s[idx / NA_][idx % NA_] = vproj[rb * NA_ + idx];
    __syncthreads();

    {
        int i = tid >> 4, j = tid & 15;
        float l = 0.f;
        #pragma unroll
        for (int a = 0; a < 32; ++a) l = fmaf(kh_s[i][a], qh_s[j][a], l);
        float mx = l;
        #pragma unroll
        for (int mm = 8; mm >= 1; mm >>= 1) mx = fmaxf(mx, __shfl_xor(mx, mm));
        float e = expf(l - mx);
        float s = e;
        #pragma unroll
        for (int mm = 8; mm >= 1; mm >>= 1) s += __shfl_xor(s, mm);
        float a = e / s;
        if (i == j) a = 0.f;
        al_s[i][j] = a;
    }
    __syncthreads();

    for (int task = tid; task < 16 * NA_; task += 256) {
        int i = task / NA_, na = task - i * NA_;
        float acc = hl[(rb + i) * NA_ + na];
        #pragma unroll
        for (int j = 0; j < 16; ++j) acc = fmaf(al_s[i][j], vp_s[j][na], acc);
        outv[(rb + i) * NA_ + na] = acc;
    }
}

extern "C" void kernel_launch(void* const* d_in, const int* in_sizes, int n_in,
                              void* d_out, int out_size, void* d_ws, size_t ws_size,
                              hipStream_t stream)
{
    (void)in_sizes; (void)n_in; (void)out_size; (void)ws_size;
    const float* inputs  = (const float*)d_in[0];
    const float* hidden  = (const float*)d_in[1];
    const float* latent  = (const float*)d_in[2];
    const float* eps     = (const float*)d_in[3];
    const float* fc1_w   = (const float*)d_in[4];
    const float* fc1_b   = (const float*)d_in[5];
    const float* w_ih    = (const float*)d_in[6];
    const float* w_hh    = (const float*)d_in[7];
    const float* b_ih    = (const float*)d_in[8];
    const float* b_hh    = (const float*)d_in[9];
    const float* lse_w1  = (const float*)d_in[10];
    const float* lse_b1  = (const float*)d_in[11];
    const float* lse_w2  = (const float*)d_in[12];
    const float* lse_b2  = (const float*)d_in[13];
    const float* me_w1   = (const float*)d_in[14];
    const float* me_b1   = (const float*)d_in[15];
    const float* me_g    = (const float*)d_in[16];
    const float* me_beta = (const float*)d_in[17];
    const float* me_w2   = (const float*)d_in[18];
    const float* me_b2   = (const float*)d_in[19];
    const float* k_w     = (const float*)d_in[20];
    const float* k_b     = (const float*)d_in[21];
    const float* q_w     = (const float*)d_in[22];
    const float* q_b     = (const float*)d_in[23];
    const float* v_w1    = (const float*)d_in[24];
    const float* v_b1    = (const float*)d_in[25];
    const float* v_w2    = (const float*)d_in[26];
    const float* v_b2    = (const float*)d_in[27];
    const float* fc2_w   = (const float*)d_in[28];
    const float* fc2_b   = (const float*)d_in[29];

    const size_t R = R_;
    // bf16 workspace region
    unsigned short* bws = (unsigned short*)d_ws;
    unsigned short* xb   = bws;              // R*128
    unsigned short* hb   = xb + R * 128;     // R*128
    unsigned short* ltb  = hb + R * 128;     // R*128
    unsigned short* leb  = ltb + R * 128;    // R*128
    unsigned short* t1b  = leb + R * 128;    // R*256
    unsigned short* pmb  = t1b + R * 256;    // R*64
    unsigned short* t3b  = pmb + R * 64;     // R*256
    unsigned short* valb = t3b + R * 256;    // R*64
    // f32 region (after 1152 bf16/row)
    float* fws  = (float*)(valb + R * 64);
    float* khf  = fws;                // R*32
    float* qhf  = khf + R * 32;       // R*32
    float* hlf  = qhf + R * 32;       // R*30
    float* vpf  = hlf + R * 30;       // R*30
    float* psum = vpf + R * 30;       // 512*256
    float* psq  = psum + 512 * 256;   // 512*256
    float* scale = psq + 512 * 256;   // 256
    float* shift = scale + 256;       // 256

    dim3 blk(256);
    dim3 g512(R_ / 64);

    // x = relu(fc1(inputs)) -> bf16
    gemm_mfma<128, 1, false, true><<<g512, blk, 0, stream>>>(inputs, 128, inputs, fc1_w, 128, fc1_b, xb, 128);
    // lt = relu(lse1(latent)) -> bf16
    gemm_mfma<64, 1, false, true><<<g512, blk, 0, stream>>>(latent, 64, latent, lse_w1, 64, lse_b1, ltb, 128);
    // h = GRU(x, hidden) -> bf16 (fused gi/gh GEMMs + combine)
    gru_gemm<<<g512, blk, 0, stream>>>(xb, hidden, w_ih, w_hh, b_ih, b_hh, hb);
    // le = lse2(lt) -> bf16
    gemm_mfma<128, 0, true, true><<<g512, blk, 0, stream>>>(ltb, 128, ltb, lse_w2, 128, lse_b2, leb, 128);
    // t1 = me1(cat(h,le)) -> bf16, + BN partial stats
    me1_stats<<<g512, blk, 0, stream>>>(hb, leb, me_w1, me_b1, t1b, psum, psq);
    bn_final_kernel<<<dim3(1), blk, 0, stream>>>(psum, psq, me_g, me_beta, scale, shift);
    // pm = clip/lrelu(me2(bn(t1))) + std*eps -> bf16 (BN in staging, pm in epilogue)
    me2pm<<<g512, blk, 0, stream>>>(t1b, scale, shift, me_w2, me_b2, eps, pmb);
    // t3 = lrelu(v1(cat(h,pm))) -> bf16
    gemm_mfma<192, 2, true, true><<<g512, blk, 0, stream>>>(hb, 128, pmb, v_w1, 192, v_b1, t3b, 256);
    // kh = norm(k(h)), qh = norm(q(pm)) -> f32 (fused)
    kq_norm<<<g512, blk, 0, stream>>>(hb, pmb, k_w, k_b, q_w, q_b, khf, qhf);
    // value = v2(t3) -> bf16
    gemm_mfma<256, 0, true, true><<<g512, blk, 0, stream>>>(t3b, 256, t3b, v_w2, 256, v_b2, valb, 64);
    // hl = fc2_w[:, :256].(h‖le) + fc2_b -> f32
    gemm_mfma<256, 0, true, false><<<g512, blk, 0, stream>>>(hb, 128, leb, fc2_w, 1280, fc2_b, hlf, NA_);
    // vproj = per-agent fc2_w slice . value
    vproj_kernel<<<dim3(16 * (BSB_ / 64)), blk, 0, stream>>>(valb, fc2_w, vpf);
    // softmax + combine -> out
    attn_combine<<<dim3(BSB_), blk, 0, stream>>>(khf, qhf, vpf, hlf, (float*)d_out);
}

// Round 5
// 171.823 us; speedup vs baseline: 5.6512x; 1.1684x over previous
//
#include <hip/hip_runtime.h>
#include <math.h>

// Problem constants (fixed instance)
namespace {
constexpr int R_ = 32768;     // BS*N rows
constexpr int N_ = 16;
constexpr int NA_ = 30;
constexpr int BSB_ = R_ / N_; // 2048 batches
}

typedef __bf16 bf16x8 __attribute__((ext_vector_type(8)));
typedef float f32x4 __attribute__((ext_vector_type(4)));

__device__ inline unsigned int f2bf(float f) {
    unsigned int u = __float_as_uint(f);
    return (u + 0x7fffu + ((u >> 16) & 1u)) >> 16;  // RTN-even
}
__device__ inline float bf2f(unsigned int us) {
    return __uint_as_float(us << 16);
}
__device__ inline unsigned int pack2(float a, float b) {
    return f2bf(a) | (f2bf(b) << 16);
}
__device__ inline uint4 pack8(float4 f0, float4 f1) {
    uint4 u;
    u.x = pack2(f0.x, f0.y); u.y = pack2(f0.z, f0.w);
    u.z = pack2(f1.x, f1.y); u.w = pack2(f1.z, f1.w);
    return u;
}
__device__ inline float sigmoidf_(float x) { return 1.f / (1.f + expf(-x)); }

// ---------------------------------------------------------------------------
// One-shot weight conversion f32 -> bf16 into workspace (concatenated).
namespace woff {
constexpr unsigned fc1 = 0;
constexpr unsigned ih  = 16384;
constexpr unsigned hh  = 65536;
constexpr unsigned l1  = 114688;
constexpr unsigned l2  = 122880;
constexpr unsigned m1  = 139264;
constexpr unsigned m2  = 204800;
constexpr unsigned kw  = 237568;
constexpr unsigned qw  = 241664;
constexpr unsigned v1  = 243712;
constexpr unsigned v2  = 292864;
constexpr unsigned f2  = 309248;
constexpr unsigned total = 347648;
}

__global__ __launch_bounds__(256)
void wcvt_kernel(const float* __restrict__ fc1_w, const float* __restrict__ w_ih,
                 const float* __restrict__ w_hh, const float* __restrict__ lse_w1,
                 const float* __restrict__ lse_w2, const float* __restrict__ me_w1,
                 const float* __restrict__ me_w2, const float* __restrict__ k_w,
                 const float* __restrict__ q_w, const float* __restrict__ v_w1,
                 const float* __restrict__ v_w2, const float* __restrict__ fc2_w,
                 unsigned short* __restrict__ dst)
{
    unsigned i = blockIdx.x * 256 + threadIdx.x;
    if (i >= woff::total) return;
    const float* src; unsigned base;
    if      (i < woff::ih) { src = fc1_w;  base = woff::fc1; }
    else if (i < woff::hh) { src = w_ih;   base = woff::ih; }
    else if (i < woff::l1) { src = w_hh;   base = woff::hh; }
    else if (i < woff::l2) { src = lse_w1; base = woff::l1; }
    else if (i < woff::m1) { src = lse_w2; base = woff::l2; }
    else if (i < woff::m2) { src = me_w1;  base = woff::m1; }
    else if (i < woff::kw) { src = me_w2;  base = woff::m2; }
    else if (i < woff::qw) { src = k_w;    base = woff::kw; }
    else if (i < woff::v1) { src = q_w;    base = woff::qw; }
    else if (i < woff::v2) { src = v_w1;   base = woff::v1; }
    else if (i < woff::f2) { src = v_w2;   base = woff::v2; }
    else                   { src = fc2_w;  base = woff::f2; }
    dst[i] = (unsigned short)f2bf(src[i - base]);
}

// ---------------------------------------------------------------------------
// Generic bf16-MFMA GEMM (used for the hl projection). W is bf16 when WBF.
template<int K, int ACT, bool ABF, bool OBF, bool WBF>
__global__ __launch_bounds__(256, 2)
void gemm_mfma(const void* __restrict__ A1v, int K1,
               const void* __restrict__ A2v,
               const void* __restrict__ Wv, int wstride,
               const float* __restrict__ bias,
               void* __restrict__ outv, int O)
{
    constexpr int KC = K / 8;
    __shared__ uint4 Atile[64 * KC];
    __shared__ uint4 Btile[64 * 8];

    const int tid = threadIdx.x;
    const int r0 = blockIdx.x * 64;

    for (int idx = tid; idx < 64 * KC; idx += 256) {
        int row = idx / KC, c = idx - row * KC;
        int k = c * 8;
        uint4 u;
        if (ABF) {
            const unsigned short* src;
            if (k < K1) src = (const unsigned short*)A1v + (size_t)(r0 + row) * K1 + k;
            else        src = (const unsigned short*)A2v + (size_t)(r0 + row) * (K - K1) + (k - K1);
            u = *(const uint4*)src;
        } else {
            const float* src;
            if (k < K1) src = (const float*)A1v + (size_t)(r0 + row) * K1 + k;
            else        src = (const float*)A2v + (size_t)(r0 + row) * (K - K1) + (k - K1);
            const float4* p = (const float4*)src;
            u = pack8(p[0], p[1]);
        }
        Atile[(row * KC + c) ^ (row & 7)] = u;
    }

    const int lane = tid & 63, w = tid >> 6;
    const int wr = w >> 1, wc = w & 1;
    const int m = lane & 15, g = lane >> 4;

    const int ntiles = (O + 63) >> 6;
    for (int ot = 0; ot < ntiles; ++ot) {
        const int o0 = ot * 64;
        f32x4 acc[2][2] = {};
        for (int kc64 = 0; kc64 < K / 64; ++kc64) {
            __syncthreads();
            for (int idx = tid; idx < 512; idx += 256) {
                int row = idx >> 3, c = idx & 7;
                int o = o0 + row;
                uint4 u = make_uint4(0, 0, 0, 0);
                if (o < O) {
                    if (WBF) {
                        u = *(const uint4*)((const unsigned short*)Wv +
                                            (size_t)o * wstride + kc64 * 64 + c * 8);
                    } else {
                        const float4* p = (const float4*)((const float*)Wv +
                                            (size_t)o * wstride + kc64 * 64 + c * 8);
                        u = pack8(p[0], p[1]);
                    }
                }
                Btile[(row * 8 + c) ^ (row & 7)] = u;
            }
            __syncthreads();
            #pragma unroll
            for (int kcl = 0; kcl < 2; ++kcl) {
                bf16x8 af[2], bfr[2];
                #pragma unroll
                for (int fr = 0; fr < 2; ++fr) {
                    int row = (wr * 2 + fr) * 16 + m;
                    int c = kc64 * 8 + kcl * 4 + g;
                    af[fr] = __builtin_bit_cast(bf16x8, Atile[(row * KC + c) ^ (row & 7)]);
                }
                #pragma unroll
                for (int fc = 0; fc < 2; ++fc) {
                    int row = (wc * 2 + fc) * 16 + m;
                    int c = kcl * 4 + g;
                    bfr[fc] = __builtin_bit_cast(bf16x8, Btile[(row * 8 + c) ^ (row & 7)]);
                }
                #pragma unroll
                for (int fr = 0; fr < 2; ++fr)
                    #pragma unroll
                    for (int fc = 0; fc < 2; ++fc)
                        acc[fr][fc] = __builtin_amdgcn_mfma_f32_16x16x32_bf16(
                            af[fr], bfr[fc], acc[fr][fc], 0, 0, 0);
            }
        }
        #pragma unroll
        for (int fc = 0; fc < 2; ++fc) {
            int col = o0 + (wc * 2 + fc) * 16 + m;
            if (col < O) {
                float bv = bias[col];
                #pragma unroll
                for (int fr = 0; fr < 2; ++fr) {
                    #pragma unroll
                    for (int i = 0; i < 4; ++i) {
                        int rowl = (wr * 2 + fr) * 16 + g * 4 + i;
                        float v = acc[fr][fc][i] + bv;
                        if (ACT == 1) v = v > 0.f ? v : 0.f;
                        if (ACT == 2) v = v > 0.f ? v : 0.01f * v;
                        size_t oi = (size_t)(r0 + rowl) * O + col;
                        if (OBF) ((unsigned short*)outv)[oi] = (unsigned short)f2bf(v);
                        else     ((float*)outv)[oi] = v;
                    }
                }
            }
        }
    }
}

// ---------------------------------------------------------------------------
// Fused fc1 + GRU. Phase 1: x = relu(inputs@fc1^T+b) -> LDS (bf16).
// Phase 2: GRU over A=[x|hidden]: rr=A.[wih_r|whh_r], zz likewise, ni=x.wih_n,
// nh=hidden.whh_n; epilogue h = ng + z*(hprev-ng) -> bf16 global.
__global__ __launch_bounds__(256, 2)
void fc1_gru(const float* __restrict__ inputs, const float* __restrict__ hidden,
             const unsigned short* __restrict__ fc1w, const float* __restrict__ fc1_b,
             const unsigned short* __restrict__ wih, const unsigned short* __restrict__ whh,
             const float* __restrict__ b_ih, const float* __restrict__ b_hh,
             unsigned short* __restrict__ hb)
{
    __shared__ uint4 Ain[64 * 16];               // inputs bf16
    __shared__ uint4 Atile[64 * 32];             // [x | hidden] bf16
    __shared__ uint4 Brr[64 * 8], Bzz[64 * 8], Bn[64 * 8];
    const int tid = threadIdx.x;
    const int r0 = blockIdx.x * 64;

    for (int idx = tid; idx < 64 * 16; idx += 256) {
        int row = idx >> 4, c = idx & 15;
        const float4* p = (const float4*)(inputs + (size_t)(r0 + row) * 128 + c * 8);
        Ain[(row * 16 + c) ^ (row & 7)] = pack8(p[0], p[1]);
    }
    for (int idx = tid; idx < 64 * 16; idx += 256) {
        int row = idx >> 4, cc = idx & 15;
        int c = 16 + cc;
        const float4* p = (const float4*)(hidden + (size_t)(r0 + row) * 128 + cc * 8);
        Atile[(row * 32 + c) ^ (row & 7)] = pack8(p[0], p[1]);
    }

    const int lane = tid & 63, w = tid >> 6;
    const int wr = w >> 1, wc = w & 1;
    const int m = lane & 15, g = lane >> 4;

    // ---- phase 1: fc1 ----
    for (int ot = 0; ot < 2; ++ot) {
        const int o0 = ot * 64;
        f32x4 acc[2][2] = {};
        for (int kc64 = 0; kc64 < 2; ++kc64) {
            __syncthreads();
            for (int idx = tid; idx < 512; idx += 256) {
                int row = idx >> 3, c = idx & 7;
                Brr[(row * 8 + c) ^ (row & 7)] =
                    *(const uint4*)(fc1w + (size_t)(o0 + row) * 128 + kc64 * 64 + c * 8);
            }
            __syncthreads();
            #pragma unroll
            for (int kcl = 0; kcl < 2; ++kcl) {
                bf16x8 af[2], bfr[2];
                #pragma unroll
                for (int fr = 0; fr < 2; ++fr) {
                    int row = (wr * 2 + fr) * 16 + m;
                    int c = kc64 * 8 + kcl * 4 + g;
                    af[fr] = __builtin_bit_cast(bf16x8, Ain[(row * 16 + c) ^ (row & 7)]);
                }
                #pragma unroll
                for (int fc = 0; fc < 2; ++fc) {
                    int row = (wc * 2 + fc) * 16 + m;
                    int c = kcl * 4 + g;
                    bfr[fc] = __builtin_bit_cast(bf16x8, Brr[(row * 8 + c) ^ (row & 7)]);
                }
                #pragma unroll
                for (int fr = 0; fr < 2; ++fr)
                    #pragma unroll
                    for (int fc = 0; fc < 2; ++fc)
                        acc[fr][fc] = __builtin_amdgcn_mfma_f32_16x16x32_bf16(
                            af[fr], bfr[fc], acc[fr][fc], 0, 0, 0);
            }
        }
        // x -> Atile cols 0..127 (bf16 LDS writes)
        #pragma unroll
        for (int fc = 0; fc < 2; ++fc) {
            int col = o0 + (wc * 2 + fc) * 16 + m;
            float bv = fc1_b[col];
            int c = col >> 3, el = col & 7;
            #pragma unroll
            for (int fr = 0; fr < 2; ++fr) {
                #pragma unroll
                for (int i = 0; i < 4; ++i) {
                    int row = (wr * 2 + fr) * 16 + g * 4 + i;
                    float v = acc[fr][fc][i] + bv;
                    v = v > 0.f ? v : 0.f;
                    ((unsigned short*)Atile)[((row * 32 + c) ^ (row & 7)) * 8 + el] =
                        (unsigned short)f2bf(v);
                }
            }
        }
    }

    // ---- phase 2: GRU ----
    for (int ot = 0; ot < 2; ++ot) {
        const int o0 = ot * 64;
        f32x4 rr[2][2] = {}, zz[2][2] = {}, ni[2][2] = {}, nh[2][2] = {};
        for (int kc64 = 0; kc64 < 4; ++kc64) {
            __syncthreads();
            const unsigned short* Wsrc = (kc64 < 2) ? wih : whh;
            const int koff = (kc64 & 1) * 64;
            for (int idx = tid; idx < 512; idx += 256) {
                int row = idx >> 3, c = idx & 7;
                int s = (row * 8 + c) ^ (row & 7);
                Brr[s] = *(const uint4*)(Wsrc + (size_t)(o0 + row) * 128 + koff + c * 8);
                Bzz[s] = *(const uint4*)(Wsrc + (size_t)(128 + o0 + row) * 128 + koff + c * 8);
                Bn[s]  = *(const uint4*)(Wsrc + (size_t)(256 + o0 + row) * 128 + koff + c * 8);
            }
            __syncthreads();
            #pragma unroll
            for (int kcl = 0; kcl < 2; ++kcl) {
                bf16x8 af[2], br_[2], bz_[2], bn_[2];
                #pragma unroll
                for (int fr = 0; fr < 2; ++fr) {
                    int row = (wr * 2 + fr) * 16 + m;
                    int c = kc64 * 8 + kcl * 4 + g;
                    af[fr] = __builtin_bit_cast(bf16x8, Atile[(row * 32 + c) ^ (row & 7)]);
                }
                #pragma unroll
                for (int fc = 0; fc < 2; ++fc) {
                    int row = (wc * 2 + fc) * 16 + m;
                    int c = kcl * 4 + g;
                    int s = (row * 8 + c) ^ (row & 7);
                    br_[fc] = __builtin_bit_cast(bf16x8, Brr[s]);
                    bz_[fc] = __builtin_bit_cast(bf16x8, Bzz[s]);
                    bn_[fc] = __builtin_bit_cast(bf16x8, Bn[s]);
                }
                #pragma unroll
                for (int fr = 0; fr < 2; ++fr)
                    #pragma unroll
                    for (int fc = 0; fc < 2; ++fc) {
                        rr[fr][fc] = __builtin_amdgcn_mfma_f32_16x16x32_bf16(af[fr], br_[fc], rr[fr][fc], 0, 0, 0);
                        zz[fr][fc] = __builtin_amdgcn_mfma_f32_16x16x32_bf16(af[fr], bz_[fc], zz[fr][fc], 0, 0, 0);
                        if (kc64 < 2)
                            ni[fr][fc] = __builtin_amdgcn_mfma_f32_16x16x32_bf16(af[fr], bn_[fc], ni[fr][fc], 0, 0, 0);
                        else
                            nh[fr][fc] = __builtin_amdgcn_mfma_f32_16x16x32_bf16(af[fr], bn_[fc], nh[fr][fc], 0, 0, 0);
                    }
            }
        }
        #pragma unroll
        for (int fc = 0; fc < 2; ++fc) {
            int c = o0 + (wc * 2 + fc) * 16 + m;
            float brz = b_ih[c] + b_hh[c];
            float bzz = b_ih[128 + c] + b_hh[128 + c];
            float bin = b_ih[256 + c], bhn = b_hh[256 + c];
            #pragma unroll
            for (int fr = 0; fr < 2; ++fr) {
                #pragma unroll
                for (int i = 0; i < 4; ++i) {
                    int row = r0 + (wr * 2 + fr) * 16 + g * 4 + i;
                    float rv = sigmoidf_(rr[fr][fc][i] + brz);
                    float zv = sigmoidf_(zz[fr][fc][i] + bzz);
                    float ng = tanhf(ni[fr][fc][i] + bin + rv * (nh[fr][fc][i] + bhn));
                    float hp = hidden[(size_t)row * 128 + c];
                    float hv = ng + zv * (hp - ng);
                    hb[(size_t)row * 128 + c] = (unsigned short)f2bf(hv);
                }
            }
        }
    }
}

// ---------------------------------------------------------------------------
// Fused lse1 + lse2: lt = relu(latent@w1^T) -> LDS; le = lt@w2^T -> bf16 global.
__global__ __launch_bounds__(256, 2)
void lse12(const float* __restrict__ latent,
           const unsigned short* __restrict__ w1b, const float* __restrict__ b1,
           const unsigned short* __restrict__ w2b, const float* __restrict__ b2,
           unsigned short* __restrict__ leb)
{
    __shared__ uint4 Alat[64 * 8];
    __shared__ uint4 Alt[64 * 16];
    __shared__ uint4 Bt[64 * 8];
    const int tid = threadIdx.x;
    const int r0 = blockIdx.x * 64;

    for (int idx = tid; idx < 64 * 8; idx += 256) {
        int row = idx >> 3, c = idx & 7;
        const float4* p = (const float4*)(latent + (size_t)(r0 + row) * 64 + c * 8);
        Alat[(row * 8 + c) ^ (row & 7)] = pack8(p[0], p[1]);
    }

    const int lane = tid & 63, w = tid >> 6;
    const int wr = w >> 1, wc = w & 1;
    const int m = lane & 15, g = lane >> 4;

    // lse1: K=64, O=128 -> Alt
    for (int ot = 0; ot < 2; ++ot) {
        const int o0 = ot * 64;
        f32x4 acc[2][2] = {};
        __syncthreads();
        for (int idx = tid; idx < 512; idx += 256) {
            int row = idx >> 3, c = idx & 7;
            Bt[(row * 8 + c) ^ (row & 7)] =
                *(const uint4*)(w1b + (size_t)(o0 + row) * 64 + c * 8);
        }
        __syncthreads();
        #pragma unroll
        for (int kcl = 0; kcl < 2; ++kcl) {
            bf16x8 af[2], bfr[2];
            #pragma unroll
            for (int fr = 0; fr < 2; ++fr) {
                int row = (wr * 2 + fr) * 16 + m;
                int c = kcl * 4 + g;
                af[fr] = __builtin_bit_cast(bf16x8, Alat[(row * 8 + c) ^ (row & 7)]);
            }
            #pragma unroll
            for (int fc = 0; fc < 2; ++fc) {
                int row = (wc * 2 + fc) * 16 + m;
                int c = kcl * 4 + g;
                bfr[fc] = __builtin_bit_cast(bf16x8, Bt[(row * 8 + c) ^ (row & 7)]);
            }
            #pragma unroll
            for (int fr = 0; fr < 2; ++fr)
                #pragma unroll
                for (int fc = 0; fc < 2; ++fc)
                    acc[fr][fc] = __builtin_amdgcn_mfma_f32_16x16x32_bf16(
                        af[fr], bfr[fc], acc[fr][fc], 0, 0, 0);
        }
        #pragma unroll
        for (int fc = 0; fc < 2; ++fc) {
            int col = o0 + (wc * 2 + fc) * 16 + m;
            float bv = b1[col];
            int c = col >> 3, el = col & 7;
            #pragma unroll
            for (int fr = 0; fr < 2; ++fr) {
                #pragma unroll
                for (int i = 0; i < 4; ++i) {
                    int row = (wr * 2 + fr) * 16 + g * 4 + i;
                    float v = acc[fr][fc][i] + bv;
                    v = v > 0.f ? v : 0.f;
                    ((unsigned short*)Alt)[((row * 16 + c) ^ (row & 7)) * 8 + el] =
                        (unsigned short)f2bf(v);
                }
            }
        }
    }

    // lse2: K=128, O=128, A=Alt -> leb
    for (int ot = 0; ot < 2; ++ot) {
        const int o0 = ot * 64;
        f32x4 acc[2][2] = {};
        for (int kc64 = 0; kc64 < 2; ++kc64) {
            __syncthreads();
            for (int idx = tid; idx < 512; idx += 256) {
                int row = idx >> 3, c = idx & 7;
                Bt[(row * 8 + c) ^ (row & 7)] =
                    *(const uint4*)(w2b + (size_t)(o0 + row) * 128 + kc64 * 64 + c * 8);
            }
            __syncthreads();
            #pragma unroll
            for (int kcl = 0; kcl < 2; ++kcl) {
                bf16x8 af[2], bfr[2];
                #pragma unroll
                for (int fr = 0; fr < 2; ++fr) {
                    int row = (wr * 2 + fr) * 16 + m;
                    int c = kc64 * 8 + kcl * 4 + g;
                    af[fr] = __builtin_bit_cast(bf16x8, Alt[(row * 16 + c) ^ (row & 7)]);
                }
                #pragma unroll
                for (int fc = 0; fc < 2; ++fc) {
                    int row = (wc * 2 + fc) * 16 + m;
                    int c = kcl * 4 + g;
                    bfr[fc] = __builtin_bit_cast(bf16x8, Bt[(row * 8 + c) ^ (row & 7)]);
                }
                #pragma unroll
                for (int fr = 0; fr < 2; ++fr)
                    #pragma unroll
                    for (int fc = 0; fc < 2; ++fc)
                        acc[fr][fc] = __builtin_amdgcn_mfma_f32_16x16x32_bf16(
                            af[fr], bfr[fc], acc[fr][fc], 0, 0, 0);
            }
        }
        #pragma unroll
        for (int fc = 0; fc < 2; ++fc) {
            int col = o0 + (wc * 2 + fc) * 16 + m;
            float bv = b2[col];
            #pragma unroll
            for (int fr = 0; fr < 2; ++fr) {
                #pragma unroll
                for (int i = 0; i < 4; ++i) {
                    int rowl = (wr * 2 + fr) * 16 + g * 4 + i;
                    float v = acc[fr][fc][i] + bv;
                    leb[(size_t)(r0 + rowl) * 128 + col] = (unsigned short)f2bf(v);
                }
            }
        }
    }
}

// ---------------------------------------------------------------------------
// me1 GEMM (K=256, O=256, A=[h|le] bf16, W bf16) + BN partial sums epilogue.
__global__ __launch_bounds__(256, 2)
void me1_stats(const unsigned short* __restrict__ hb, const unsigned short* __restrict__ leb,
               const unsigned short* __restrict__ W, const float* __restrict__ bias,
               unsigned short* __restrict__ t1,
               float* __restrict__ psum, float* __restrict__ psq)
{
    __shared__ uint4 Atile[64 * 32];
    __shared__ uint4 Btile[64 * 8];
    __shared__ float sredS[2][2][2][16];
    __shared__ float sredQ[2][2][2][16];
    const int tid = threadIdx.x;
    const int r0 = blockIdx.x * 64;

    for (int idx = tid; idx < 64 * 32; idx += 256) {
        int row = idx >> 5, c = idx & 31;
        const unsigned short* src = (c < 16)
            ? hb + (size_t)(r0 + row) * 128 + c * 8
            : leb + (size_t)(r0 + row) * 128 + (c - 16) * 8;
        Atile[(row * 32 + c) ^ (row & 7)] = *(const uint4*)src;
    }

    const int lane = tid & 63, w = tid >> 6;
    const int wr = w >> 1, wc = w & 1;
    const int m = lane & 15, g = lane >> 4;

    for (int ot = 0; ot < 4; ++ot) {
        const int o0 = ot * 64;
        f32x4 acc[2][2] = {};
        for (int kc64 = 0; kc64 < 4; ++kc64) {
            __syncthreads();
            for (int idx = tid; idx < 512; idx += 256) {
                int row = idx >> 3, c = idx & 7;
                Btile[(row * 8 + c) ^ (row & 7)] =
                    *(const uint4*)(W + (size_t)(o0 + row) * 256 + kc64 * 64 + c * 8);
            }
            __syncthreads();
            #pragma unroll
            for (int kcl = 0; kcl < 2; ++kcl) {
                bf16x8 af[2], bfr[2];
                #pragma unroll
                for (int fr = 0; fr < 2; ++fr) {
                    int row = (wr * 2 + fr) * 16 + m;
                    int c = kc64 * 8 + kcl * 4 + g;
                    af[fr] = __builtin_bit_cast(bf16x8, Atile[(row * 32 + c) ^ (row & 7)]);
                }
                #pragma unroll
                for (int fc = 0; fc < 2; ++fc) {
                    int row = (wc * 2 + fc) * 16 + m;
                    int c = kcl * 4 + g;
                    bfr[fc] = __builtin_bit_cast(bf16x8, Btile[(row * 8 + c) ^ (row & 7)]);
                }
                #pragma unroll
                for (int fr = 0; fr < 2; ++fr)
                    #pragma unroll
                    for (int fc = 0; fc < 2; ++fc)
                        acc[fr][fc] = __builtin_amdgcn_mfma_f32_16x16x32_bf16(
                            af[fr], bfr[fc], acc[fr][fc], 0, 0, 0);
            }
        }
        #pragma unroll
        for (int fc = 0; fc < 2; ++fc) {
            int col = o0 + (wc * 2 + fc) * 16 + m;
            float bv = bias[col];
            float s = 0.f, q = 0.f;
            #pragma unroll
            for (int fr = 0; fr < 2; ++fr) {
                #pragma unroll
                for (int i = 0; i < 4; ++i) {
                    int rowl = (wr * 2 + fr) * 16 + g * 4 + i;
                    float v = acc[fr][fc][i] + bv;
                    t1[(size_t)(r0 + rowl) * 256 + col] = (unsigned short)f2bf(v);
                    s += v; q += v * v;
                }
            }
            s += __shfl_xor(s, 16); s += __shfl_xor(s, 32);
            q += __shfl_xor(q, 16); q += __shfl_xor(q, 32);
            if (lane < 16) { sredS[wr][wc][fc][m] = s; sredQ[wr][wc][fc][m] = q; }
        }
        __syncthreads();
        if (tid < 64) {
            int wcfc = tid >> 4, mm = tid & 15;
            int wc2 = wcfc >> 1, fc2 = wcfc & 1;
            psum[(size_t)blockIdx.x * 256 + o0 + tid] =
                sredS[0][wc2][fc2][mm] + sredS[1][wc2][fc2][mm];
            psq[(size_t)blockIdx.x * 256 + o0 + tid] =
                sredQ[0][wc2][fc2][mm] + sredQ[1][wc2][fc2][mm];
        }
    }
}

__global__ __launch_bounds__(256)
void bn_final_kernel(const float* __restrict__ psum, const float* __restrict__ psq,
                     const float* __restrict__ g, const float* __restrict__ beta,
                     float* __restrict__ scale, float* __restrict__ shift)
{
    int f = threadIdx.x;
    float s = 0.f, ss = 0.f;
    #pragma unroll 8
    for (int b = 0; b < 512; ++b) { s += psum[(size_t)b * 256 + f]; ss += psq[(size_t)b * 256 + f]; }
    float mean = s / (float)R_;
    float var = ss / (float)R_ - mean * mean;
    float istd = rsqrtf(var + 1e-5f);
    float sc = g[f] * istd;
    scale[f] = sc;
    shift[f] = beta[f] - mean * sc;
}

// ---------------------------------------------------------------------------
// me2 GEMM with BN+lrelu in A-staging; epilogue computes pm (bf16).
__global__ __launch_bounds__(256, 2)
void me2pm(const unsigned short* __restrict__ t1,
           const float* __restrict__ scale, const float* __restrict__ shift,
           const unsigned short* __restrict__ W, const float* __restrict__ bias,
           const float* __restrict__ eps, unsigned short* __restrict__ pm)
{
    __shared__ uint4 Atile[64 * 32];
    __shared__ uint4 Btile[64 * 8];
    __shared__ float sc_s[256], sh_s[256];
    const int tid = threadIdx.x;
    const int r0 = blockIdx.x * 64;

    sc_s[tid] = scale[tid];
    sh_s[tid] = shift[tid];
    __syncthreads();

    for (int idx = tid; idx < 64 * 32; idx += 256) {
        int row = idx >> 5, c = idx & 31;
        uint4 u = *(const uint4*)(t1 + (size_t)(r0 + row) * 256 + c * 8);
        unsigned int vv[4] = {u.x, u.y, u.z, u.w};
        float f[8];
        #pragma unroll
        for (int q2 = 0; q2 < 4; ++q2) {
            f[2 * q2]     = __uint_as_float((vv[q2] & 0xffffu) << 16);
            f[2 * q2 + 1] = __uint_as_float(vv[q2] & 0xffff0000u);
        }
        int k = c * 8;
        #pragma unroll
        for (int j = 0; j < 8; ++j) {
            float v = f[j] * sc_s[k + j] + sh_s[k + j];
            f[j] = v > 0.f ? v : 0.01f * v;
        }
        uint4 r;
        r.x = pack2(f[0], f[1]); r.y = pack2(f[2], f[3]);
        r.z = pack2(f[4], f[5]); r.w = pack2(f[6], f[7]);
        Atile[(row * 32 + c) ^ (row & 7)] = r;
    }

    const int lane = tid & 63, w = tid >> 6;
    const int wr = w >> 1, wc = w & 1;
    const int m = lane & 15, g = lane >> 4;

    float msave[2][2][4];
    for (int ot = 0; ot < 2; ++ot) {
        const int o0 = ot * 64;
        f32x4 acc[2][2] = {};
        for (int kc64 = 0; kc64 < 4; ++kc64) {
            __syncthreads();
            for (int idx = tid; idx < 512; idx += 256) {
                int row = idx >> 3, c = idx & 7;
                Btile[(row * 8 + c) ^ (row & 7)] =
                    *(const uint4*)(W + (size_t)(o0 + row) * 256 + kc64 * 64 + c * 8);
            }
            __syncthreads();
            #pragma unroll
            for (int kcl = 0; kcl < 2; ++kcl) {
                bf16x8 af[2], bfr[2];
                #pragma unroll
                for (int fr = 0; fr < 2; ++fr) {
                    int row = (wr * 2 + fr) * 16 + m;
                    int c = kc64 * 8 + kcl * 4 + g;
                    af[fr] = __builtin_bit_cast(bf16x8, Atile[(row * 32 + c) ^ (row & 7)]);
                }
                #pragma unroll
                for (int fc = 0; fc < 2; ++fc) {
                    int row = (wc * 2 + fc) * 16 + m;
                    int c = kcl * 4 + g;
                    bfr[fc] = __builtin_bit_cast(bf16x8, Btile[(row * 8 + c) ^ (row & 7)]);
                }
                #pragma unroll
                for (int fr = 0; fr < 2; ++fr)
                    #pragma unroll
                    for (int fc = 0; fc < 2; ++fc)
                        acc[fr][fc] = __builtin_amdgcn_mfma_f32_16x16x32_bf16(
                            af[fr], bfr[fc], acc[fr][fc], 0, 0, 0);
            }
        }
        #pragma unroll
        for (int fc = 0; fc < 2; ++fc) {
            int cp = (wc * 2 + fc) * 16 + m;
            float bv = bias[o0 + cp];
            #pragma unroll
            for (int fr = 0; fr < 2; ++fr) {
                #pragma unroll
                for (int i = 0; i < 4; ++i) {
                    float v = acc[fr][fc][i] + bv;
                    v = v > 0.f ? v : 0.01f * v;
                    if (ot == 0) {
                        msave[fc][fr][i] = fminf(fmaxf(v, -1.f), 1.f);
                    } else {
                        float sd = fminf(fmaxf(v, 0.5f), 1.f);
                        int row = r0 + (wr * 2 + fr) * 16 + g * 4 + i;
                        float e = eps[(size_t)row * 64 + cp];
                        pm[(size_t)row * 64 + cp] =
                            (unsigned short)f2bf(msave[fc][fr][i] + sd * e);
                    }
                }
            }
        }
    }
}

// ---------------------------------------------------------------------------
// Fused v1 + v2: t3 = lrelu(v1([h|pm])) -> LDS; value = v2(t3) -> bf16 global.
__global__ __launch_bounds__(256, 2)
void v12(const unsigned short* __restrict__ hb, const unsigned short* __restrict__ pmb,
         const unsigned short* __restrict__ v1w, const float* __restrict__ v1_b,
         const unsigned short* __restrict__ v2w, const float* __restrict__ v2_b,
         unsigned short* __restrict__ valb)
{
    __shared__ uint4 A1[64 * 24];   // [h(128) | pm(64)]
    __shared__ uint4 A3[64 * 32];   // t3
    __shared__ uint4 Bt[64 * 8];
    const int tid = threadIdx.x;
    const int r0 = blockIdx.x * 64;

    for (int idx = tid; idx < 64 * 24; idx += 256) {
        int row = idx / 24, c = idx - row * 24;
        const unsigned short* src = (c < 16)
            ? hb + (size_t)(r0 + row) * 128 + c * 8
            : pmb + (size_t)(r0 + row) * 64 + (c - 16) * 8;
        A1[(row * 24 + c) ^ (row & 7)] = *(const uint4*)src;
    }

    const int lane = tid & 63, w = tid >> 6;
    const int wr = w >> 1, wc = w & 1;
    const int m = lane & 15, g = lane >> 4;

    // v1: K=192, O=256 -> A3
    for (int ot = 0; ot < 4; ++ot) {
        const int o0 = ot * 64;
        f32x4 acc[2][2] = {};
        for (int kc64 = 0; kc64 < 3; ++kc64) {
            __syncthreads();
            for (int idx = tid; idx < 512; idx += 256) {
                int row = idx >> 3, c = idx & 7;
                Bt[(row * 8 + c) ^ (row & 7)] =
                    *(const uint4*)(v1w + (size_t)(o0 + row) * 192 + kc64 * 64 + c * 8);
            }
            __syncthreads();
            #pragma unroll
            for (int kcl = 0; kcl < 2; ++kcl) {
                bf16x8 af[2], bfr[2];
                #pragma unroll
                for (int fr = 0; fr < 2; ++fr) {
                    int row = (wr * 2 + fr) * 16 + m;
                    int c = kc64 * 8 + kcl * 4 + g;
                    af[fr] = __builtin_bit_cast(bf16x8, A1[(row * 24 + c) ^ (row & 7)]);
                }
                #pragma unroll
                for (int fc = 0; fc < 2; ++fc) {
                    int row = (wc * 2 + fc) * 16 + m;
                    int c = kcl * 4 + g;
                    bfr[fc] = __builtin_bit_cast(bf16x8, Bt[(row * 8 + c) ^ (row & 7)]);
                }
                #pragma unroll
                for (int fr = 0; fr < 2; ++fr)
                    #pragma unroll
                    for (int fc = 0; fc < 2; ++fc)
                        acc[fr][fc] = __builtin_amdgcn_mfma_f32_16x16x32_bf16(
                            af[fr], bfr[fc], acc[fr][fc], 0, 0, 0);
            }
        }
        #pragma unroll
        for (int fc = 0; fc < 2; ++fc) {
            int col = o0 + (wc * 2 + fc) * 16 + m;
            float bv = v1_b[col];
            int c = col >> 3, el = col & 7;
            #pragma unroll
            for (int fr = 0; fr < 2; ++fr) {
                #pragma unroll
                for (int i = 0; i < 4; ++i) {
                    int row = (wr * 2 + fr) * 16 + g * 4 + i;
                    float v = acc[fr][fc][i] + bv;
                    v = v > 0.f ? v : 0.01f * v;
                    ((unsigned short*)A3)[((row * 32 + c) ^ (row & 7)) * 8 + el] =
                        (unsigned short)f2bf(v);
                }
            }
        }
    }

    // v2: K=256, O=64, A=A3 -> valb
    {
        f32x4 acc[2][2] = {};
        for (int kc64 = 0; kc64 < 4; ++kc64) {
            __syncthreads();
            for (int idx = tid; idx < 512; idx += 256) {
                int row = idx >> 3, c = idx & 7;
                Bt[(row * 8 + c) ^ (row & 7)] =
                    *(const uint4*)(v2w + (size_t)row * 256 + kc64 * 64 + c * 8);
            }
            __syncthreads();
            #pragma unroll
            for (int kcl = 0; kcl < 2; ++kcl) {
                bf16x8 af[2], bfr[2];
                #pragma unroll
                for (int fr = 0; fr < 2; ++fr) {
                    int row = (wr * 2 + fr) * 16 + m;
                    int c = kc64 * 8 + kcl * 4 + g;
                    af[fr] = __builtin_bit_cast(bf16x8, A3[(row * 32 + c) ^ (row & 7)]);
                }
                #pragma unroll
                for (int fc = 0; fc < 2; ++fc) {
                    int row = (wc * 2 + fc) * 16 + m;
                    int c = kcl * 4 + g;
                    bfr[fc] = __builtin_bit_cast(bf16x8, Bt[(row * 8 + c) ^ (row & 7)]);
                }
                #pragma unroll
                for (int fr = 0; fr < 2; ++fr)
                    #pragma unroll
                    for (int fc = 0; fc < 2; ++fc)
                        acc[fr][fc] = __builtin_amdgcn_mfma_f32_16x16x32_bf16(
                            af[fr], bfr[fc], acc[fr][fc], 0, 0, 0);
            }
        }
        #pragma unroll
        for (int fc = 0; fc < 2; ++fc) {
            int col = (wc * 2 + fc) * 16 + m;
            float bv = v2_b[col];
            #pragma unroll
            for (int fr = 0; fr < 2; ++fr) {
                #pragma unroll
                for (int i = 0; i < 4; ++i) {
                    int rowl = (wr * 2 + fr) * 16 + g * 4 + i;
                    float v = acc[fr][fc][i] + bv;
                    valb[(size_t)(r0 + rowl) * 64 + col] = (unsigned short)f2bf(v);
                }
            }
        }
    }
}

// ---------------------------------------------------------------------------
// k(h) and q(pm) GEMMs + cosine row-normalization, fused (bf16 weights).
__global__ __launch_bounds__(256, 2)
void kq_norm(const unsigned short* __restrict__ hb, const unsigned short* __restrict__ pmb,
             const unsigned short* __restrict__ kwb, const float* __restrict__ k_b,
             const unsigned short* __restrict__ qwb, const float* __restrict__ q_b,
             float* __restrict__ kh, float* __restrict__ qh)
{
    __shared__ uint4 Ah[64 * 16];
    __shared__ uint4 Apm[64 * 8];
    __shared__ uint4 Bk[32 * 16];
    __shared__ uint4 Bq[32 * 8];
    const int tid = threadIdx.x;
    const int r0 = blockIdx.x * 64;

    for (int idx = tid; idx < 64 * 16; idx += 256) {
        int row = idx >> 4, c = idx & 15;
        Ah[(row * 16 + c) ^ (row & 7)] = *(const uint4*)(hb + (size_t)(r0 + row) * 128 + c * 8);
    }
    for (int idx = tid; idx < 64 * 8; idx += 256) {
        int row = idx >> 3, c = idx & 7;
        Apm[(row * 8 + c) ^ (row & 7)] = *(const uint4*)(pmb + (size_t)(r0 + row) * 64 + c * 8);
    }
    for (int idx = tid; idx < 32 * 16; idx += 256) {
        int row = idx >> 4, c = idx & 15;
        Bk[(row * 16 + c) ^ (row & 7)] = *(const uint4*)(kwb + (size_t)row * 128 + c * 8);
    }
    for (int idx = tid; idx < 32 * 8; idx += 256) {
        int row = idx >> 3, c = idx & 7;
        Bq[(row * 8 + c) ^ (row & 7)] = *(const uint4*)(qwb + (size_t)row * 64 + c * 8);
    }
    __syncthreads();

    const int lane = tid & 63, w = tid >> 6;
    const int m = lane & 15, g = lane >> 4;
    const bool isq = w >= 2;
    const int half = w & 1;

    f32x4 acc[2][2] = {};
    const int nks = isq ? 2 : 4;
    for (int ks = 0; ks < nks; ++ks) {
        bf16x8 af[2], bfr[2];
        #pragma unroll
        for (int fr = 0; fr < 2; ++fr) {
            int row = half * 32 + fr * 16 + m;
            int c = ks * 4 + g;
            af[fr] = __builtin_bit_cast(bf16x8,
                isq ? Apm[(row * 8 + c) ^ (row & 7)] : Ah[(row * 16 + c) ^ (row & 7)]);
        }
        #pragma unroll
        for (int fc = 0; fc < 2; ++fc) {
            int row = fc * 16 + m;
            int c = ks * 4 + g;
            bfr[fc] = __builtin_bit_cast(bf16x8,
                isq ? Bq[(row * 8 + c) ^ (row & 7)] : Bk[(row * 16 + c) ^ (row & 7)]);
        }
        #pragma unroll
        for (int fr = 0; fr < 2; ++fr)
            #pragma unroll
            for (int fc = 0; fc < 2; ++fc)
                acc[fr][fc] = __builtin_amdgcn_mfma_f32_16x16x32_bf16(
                    af[fr], bfr[fc], acc[fr][fc], 0, 0, 0);
    }

    const float* bias = isq ? q_b : k_b;
    float b0 = bias[m], b1 = bias[16 + m];
    float* outp = isq ? qh : kh;
    #pragma unroll
    for (int fr = 0; fr < 2; ++fr) {
        #pragma unroll
        for (int i = 0; i < 4; ++i) {
            float v0 = acc[fr][0][i] + b0;
            float v1 = acc[fr][1][i] + b1;
            float ss = v0 * v0 + v1 * v1;
            ss += __shfl_xor(ss, 1); ss += __shfl_xor(ss, 2);
            ss += __shfl_xor(ss, 4); ss += __shfl_xor(ss, 8);
            float inv = 1.f / fmaxf(sqrtf(ss), 1e-8f);
            int row = r0 + half * 32 + fr * 16 + g * 4 + i;
            outp[(size_t)row * 32 + m] = v0 * inv;
            outp[(size_t)row * 32 + 16 + m] = v1 * inv;
        }
    }
}

// ---------------------------------------------------------------------------
// vproj[r][na] = w2[na, 256+64*(r%16) .. +64] . value[r]   (value bf16, w2 f32)
__global__ __launch_bounds__(256)
void vproj_kernel(const unsigned short* __restrict__ value, const float* __restrict__ w2,
                  float* __restrict__ vproj)
{
    __shared__ float w2s[NA_][65];
    __shared__ float val_s[64][65];
    const int tid = threadIdx.x;
    const int j = blockIdx.x & 15;
    const int b0 = (blockIdx.x >> 4) * 64;

    for (int idx = tid; idx < NA_ * 64; idx += 256) {
        int na = idx >> 6, k = idx & 63;
        w2s[na][k] = w2[(size_t)na * 1280 + 256 + j * 64 + k];
    }
    for (int idx = tid; idx < 64 * 64; idx += 256) {
        int bl = idx >> 6, k = idx & 63;
        val_s[bl][k] = bf2f(value[((size_t)(b0 + bl) * 16 + j) * 64 + k]);
    }
    __syncthreads();

    for (int task = tid; task < 64 * NA_; task += 256) {
        int bl = task / NA_, na = task - bl * NA_;
        float acc = 0.f;
        #pragma unroll 16
        for (int k = 0; k < 64; ++k) acc = fmaf(val_s[bl][k], w2s[na][k], acc);
        vproj[((size_t)(b0 + bl) * 16 + j) * NA_ + na] = acc;
    }
}

// Per batch: cosine logits (16x16), softmax over j, zero diag, combine.
__global__ __launch_bounds__(256)
void attn_combine(const float* __restrict__ kh, const float* __restrict__ qh,
                  const float* __restrict__ vproj, const float* __restrict__ hl,
                  float* __restrict__ outv)
{
    __shared__ float kh_s[16][33], qh_s[16][33];
    __shared__ float al_s[16][16];
    __shared__ float vp_s[16][NA_];
    const int tid = threadIdx.x;
    const size_t rb = (size_t)blockIdx.x * 16;

    for (int idx = tid; idx < 512; idx += 256) {
        int r = idx >> 5, a = idx & 31;
        kh_s[r][a] = kh[rb * 32 + idx];
        qh_s[r][a] = qh[rb * 32 + idx];
    }
    for (int idx = tid; idx < 16 * NA_; idx += 256)
        vp_s[idx / NA_][idx % NA_] = vproj[rb * NA_ + idx];
    __syncthreads();

    {
        int i = tid >> 4, j = tid & 15;
        float l = 0.f;
        #pragma unroll
        for (int a = 0; a < 32; ++a) l = fmaf(kh_s[i][a], qh_s[j][a], l);
        float mx = l;
        #pragma unroll
        for (int mm = 8; mm >= 1; mm >>= 1) mx = fmaxf(mx, __shfl_xor(mx, mm));
        float e = expf(l - mx);
        float s = e;
        #pragma unroll
        for (int mm = 8; mm >= 1; mm >>= 1) s += __shfl_xor(s, mm);
        float a = e / s;
        if (i == j) a = 0.f;
        al_s[i][j] = a;
    }
    __syncthreads();

    for (int task = tid; task < 16 * NA_; task += 256) {
        int i = task / NA_, na = task - i * NA_;
        float acc = hl[(rb + i) * NA_ + na];
        #pragma unroll
        for (int j = 0; j < 16; ++j) acc = fmaf(al_s[i][j], vp_s[j][na], acc);
        outv[(rb + i) * NA_ + na] = acc;
    }
}

extern "C" void kernel_launch(void* const* d_in, const int* in_sizes, int n_in,
                              void* d_out, int out_size, void* d_ws, size_t ws_size,
                              hipStream_t stream)
{
    (void)in_sizes; (void)n_in; (void)out_size; (void)ws_size;
    const float* inputs  = (const float*)d_in[0];
    const float* hidden  = (const float*)d_in[1];
    const float* latent  = (const float*)d_in[2];
    const float* eps     = (const float*)d_in[3];
    const float* fc1_w   = (const float*)d_in[4];
    const float* fc1_b   = (const float*)d_in[5];
    const float* w_ih    = (const float*)d_in[6];
    const float* w_hh    = (const float*)d_in[7];
    const float* b_ih    = (const float*)d_in[8];
    const float* b_hh    = (const float*)d_in[9];
    const float* lse_w1  = (const float*)d_in[10];
    const float* lse_b1  = (const float*)d_in[11];
    const float* lse_w2  = (const float*)d_in[12];
    const float* lse_b2  = (const float*)d_in[13];
    const float* me_w1   = (const float*)d_in[14];
    const float* me_b1   = (const float*)d_in[15];
    const float* me_g    = (const float*)d_in[16];
    const float* me_beta = (const float*)d_in[17];
    const float* me_w2   = (const float*)d_in[18];
    const float* me_b2   = (const float*)d_in[19];
    const float* k_w     = (const float*)d_in[20];
    const float* k_b     = (const float*)d_in[21];
    const float* q_w     = (const float*)d_in[22];
    const float* q_b     = (const float*)d_in[23];
    const float* v_w1    = (const float*)d_in[24];
    const float* v_b1    = (const float*)d_in[25];
    const float* v_w2    = (const float*)d_in[26];
    const float* v_b2    = (const float*)d_in[27];
    const float* fc2_w   = (const float*)d_in[28];
    const float* fc2_b   = (const float*)d_in[29];

    const size_t R = R_;
    // Workspace layout: bf16 activations, bf16 weights, then f32 buffers.
    unsigned short* bws = (unsigned short*)d_ws;
    unsigned short* hb   = bws;               // R*128
    unsigned short* leb  = hb + R * 128;      // R*128
    unsigned short* t1b  = leb + R * 128;     // R*256
    unsigned short* pmb  = t1b + R * 256;     // R*64
    unsigned short* valb = pmb + R * 64;      // R*64
    unsigned short* wb   = valb + R * 64;     // 347648 (bf16 weights)
    float* fws  = (float*)(wb + woff::total);
    float* khf  = fws;                 // R*32
    float* qhf  = khf + R * 32;        // R*32
    float* hlf  = qhf + R * 32;        // R*30
    float* vpf  = hlf + R * 30;        // R*30
    float* psum = vpf + R * 30;        // 512*256
    float* psq  = psum + 512 * 256;    // 512*256
    float* scale = psq + 512 * 256;    // 256
    float* shift = scale + 256;        // 256

    dim3 blk(256);
    dim3 g512(R_ / 64);

    // 0) weights -> bf16 (once per call; cheap)
    wcvt_kernel<<<dim3((woff::total + 255) / 256), blk, 0, stream>>>(
        fc1_w, w_ih, w_hh, lse_w1, lse_w2, me_w1, me_w2, k_w, q_w, v_w1, v_w2, fc2_w, wb);

    // 1) x = relu(fc1(inputs)) [LDS]; h = GRU(x, hidden) -> bf16
    fc1_gru<<<g512, blk, 0, stream>>>(inputs, hidden, wb + woff::fc1, fc1_b,
                                      wb + woff::ih, wb + woff::hh, b_ih, b_hh, hb);
    // 2) lt = relu(lse1(latent)) [LDS]; le = lse2(lt) -> bf16
    lse12<<<g512, blk, 0, stream>>>(latent, wb + woff::l1, lse_b1,
                                    wb + woff::l2, lse_b2, leb);
    // 3) t1 = me1(cat(h,le)) -> bf16 + BN partial stats
    me1_stats<<<g512, blk, 0, stream>>>(hb, leb, wb + woff::m1, me_b1, t1b, psum, psq);
    bn_final_kernel<<<dim3(1), blk, 0, stream>>>(psum, psq, me_g, me_beta, scale, shift);
    // 4) pm = clip(lrelu(me2(bn(t1)))) + std*eps -> bf16
    me2pm<<<g512, blk, 0, stream>>>(t1b, scale, shift, wb + woff::m2, me_b2, eps, pmb);
    // 5) t3 = lrelu(v1([h|pm])) [LDS]; value = v2(t3) -> bf16
    v12<<<g512, blk, 0, stream>>>(hb, pmb, wb + woff::v1, v_b1,
                                  wb + woff::v2, v_b2, valb);
    // 6) kh = norm(k(h)), qh = norm(q(pm)) -> f32
    kq_norm<<<g512, blk, 0, stream>>>(hb, pmb, wb + woff::kw, k_b, wb + woff::qw, q_b, khf, qhf);
    // 7) hl = fc2_w[:, :256].(h‖le) + fc2_b -> f32
    gemm_mfma<256, 0, true, false, true><<<g512, blk, 0, stream>>>(
        hb, 128, leb, wb + woff::f2, 1280, fc2_b, hlf, NA_);
    // 8) vproj = per-agent fc2_w slice . value
    vproj_kernel<<<dim3(16 * (BSB_ / 64)), blk, 0, stream>>>(valb, fc2_w, vpf);
    // 9) softmax + combine -> out
    attn_combine<<<dim3(BSB_), blk, 0, stream>>>(khf, qhf, vpf, hlf, (float*)d_out);
}

// Round 6
// 171.620 us; speedup vs baseline: 5.6579x; 1.0012x over previous
//
#include <hip/hip_runtime.h>
#include <math.h>

// Problem constants (fixed instance)
namespace {
constexpr int R_ = 32768;     // BS*N rows
constexpr int N_ = 16;
constexpr int NA_ = 30;
constexpr int BSB_ = R_ / N_; // 2048 batches
}

typedef __bf16 bf16x8 __attribute__((ext_vector_type(8)));
typedef float f32x4 __attribute__((ext_vector_type(4)));

__device__ inline unsigned int f2bf(float f) {
    unsigned int u = __float_as_uint(f);
    return (u + 0x7fffu + ((u >> 16) & 1u)) >> 16;  // RTN-even
}
__device__ inline float bf2f(unsigned int us) {
    return __uint_as_float(us << 16);
}
__device__ inline unsigned int pack2(float a, float b) {
    return f2bf(a) | (f2bf(b) << 16);
}
__device__ inline uint4 pack8(float4 f0, float4 f1) {
    uint4 u;
    u.x = pack2(f0.x, f0.y); u.y = pack2(f0.z, f0.w);
    u.z = pack2(f1.x, f1.y); u.w = pack2(f1.z, f1.w);
    return u;
}
__device__ inline float sigmoidf_(float x) { return 1.f / (1.f + expf(-x)); }

// A fragment from swizzled LDS tile (KC = 16B-chunks per row)
__device__ __forceinline__ bf16x8 lda_frag(const uint4* At, int KC, int row, int c) {
    return __builtin_bit_cast(bf16x8, At[(row * KC + c) ^ (row & 7)]);
}
// B fragment direct from global bf16 weights (row-major, rstride elements/row)
__device__ __forceinline__ bf16x8 ldb_frag(const unsigned short* W, int row, int rstride, int c) {
    return __builtin_bit_cast(bf16x8, *(const uint4*)(W + (size_t)row * rstride + (size_t)c * 8));
}

// ---------------------------------------------------------------------------
// One-shot weight conversion f32 -> bf16 into workspace (concatenated).
namespace woff {
constexpr unsigned fc1 = 0;
constexpr unsigned ih  = 16384;
constexpr unsigned hh  = 65536;
constexpr unsigned l1  = 114688;
constexpr unsigned l2  = 122880;
constexpr unsigned m1  = 139264;
constexpr unsigned m2  = 204800;
constexpr unsigned kw  = 237568;
constexpr unsigned qw  = 241664;
constexpr unsigned v1  = 243712;
constexpr unsigned v2  = 292864;
constexpr unsigned f2  = 309248;
constexpr unsigned total = 347648;
}

__global__ __launch_bounds__(256)
void wcvt_kernel(const float* __restrict__ fc1_w, const float* __restrict__ w_ih,
                 const float* __restrict__ w_hh, const float* __restrict__ lse_w1,
                 const float* __restrict__ lse_w2, const float* __restrict__ me_w1,
                 const float* __restrict__ me_w2, const float* __restrict__ k_w,
                 const float* __restrict__ q_w, const float* __restrict__ v_w1,
                 const float* __restrict__ v_w2, const float* __restrict__ fc2_w,
                 unsigned short* __restrict__ dst)
{
    unsigned i = blockIdx.x * 256 + threadIdx.x;
    if (i >= woff::total) return;
    const float* src; unsigned base;
    if      (i < woff::ih) { src = fc1_w;  base = woff::fc1; }
    else if (i < woff::hh) { src = w_ih;   base = woff::ih; }
    else if (i < woff::l1) { src = w_hh;   base = woff::hh; }
    else if (i < woff::l2) { src = lse_w1; base = woff::l1; }
    else if (i < woff::m1) { src = lse_w2; base = woff::l2; }
    else if (i < woff::m2) { src = me_w1;  base = woff::m1; }
    else if (i < woff::kw) { src = me_w2;  base = woff::m2; }
    else if (i < woff::qw) { src = k_w;    base = woff::kw; }
    else if (i < woff::v1) { src = q_w;    base = woff::qw; }
    else if (i < woff::v2) { src = v_w1;   base = woff::v1; }
    else if (i < woff::f2) { src = v_w2;   base = woff::v2; }
    else                   { src = fc2_w;  base = woff::f2; }
    dst[i] = (unsigned short)f2bf(src[i - base]);
}

// ---------------------------------------------------------------------------
// Fused fc1 + GRU. Phase 1: x = relu(inputs@fc1^T+b) -> LDS.
// Phase 2: A=[x|hidden]; rr=A.[wih_r|whh_r], zz likewise, ni=x.wih_n,
// nh=hidden.whh_n; epilogue h = ng + z*(hprev-ng) -> bf16 global.
// B fragments read directly from L2-resident bf16 weights (no staging/barriers).
__global__ __launch_bounds__(256, 2)
void fc1_gru(const float* __restrict__ inputs, const float* __restrict__ hidden,
             const unsigned short* __restrict__ fc1w, const float* __restrict__ fc1_b,
             const unsigned short* __restrict__ wih, const unsigned short* __restrict__ whh,
             const float* __restrict__ b_ih, const float* __restrict__ b_hh,
             unsigned short* __restrict__ hb)
{
    __shared__ uint4 Ain[64 * 16];    // inputs bf16
    __shared__ uint4 Atile[64 * 32];  // [x | hidden] bf16
    const int tid = threadIdx.x;
    const int r0 = blockIdx.x * 64;

    for (int idx = tid; idx < 64 * 16; idx += 256) {
        int row = idx >> 4, c = idx & 15;
        const float4* p = (const float4*)(inputs + (size_t)(r0 + row) * 128 + c * 8);
        Ain[(row * 16 + c) ^ (row & 7)] = pack8(p[0], p[1]);
    }
    for (int idx = tid; idx < 64 * 16; idx += 256) {
        int row = idx >> 4, cc = idx & 15;
        int c = 16 + cc;
        const float4* p = (const float4*)(hidden + (size_t)(r0 + row) * 128 + cc * 8);
        Atile[(row * 32 + c) ^ (row & 7)] = pack8(p[0], p[1]);
    }
    __syncthreads();

    const int lane = tid & 63, w = tid >> 6;
    const int wr = w >> 1, wc = w & 1;
    const int m = lane & 15, g = lane >> 4;

    // ---- phase 1: fc1 (K=128) ----
    for (int ot = 0; ot < 2; ++ot) {
        const int o0 = ot * 64;
        f32x4 acc[2][2] = {};
        #pragma unroll
        for (int ks = 0; ks < 4; ++ks) {
            bf16x8 af[2], bf[2];
            #pragma unroll
            for (int fr = 0; fr < 2; ++fr)
                af[fr] = lda_frag(Ain, 16, (wr * 2 + fr) * 16 + m, ks * 4 + g);
            #pragma unroll
            for (int fc = 0; fc < 2; ++fc)
                bf[fc] = ldb_frag(fc1w, o0 + (wc * 2 + fc) * 16 + m, 128, ks * 4 + g);
            #pragma unroll
            for (int fr = 0; fr < 2; ++fr)
                #pragma unroll
                for (int fc = 0; fc < 2; ++fc)
                    acc[fr][fc] = __builtin_amdgcn_mfma_f32_16x16x32_bf16(
                        af[fr], bf[fc], acc[fr][fc], 0, 0, 0);
        }
        #pragma unroll
        for (int fc = 0; fc < 2; ++fc) {
            int col = o0 + (wc * 2 + fc) * 16 + m;
            float bv = fc1_b[col];
            int c = col >> 3, el = col & 7;
            #pragma unroll
            for (int fr = 0; fr < 2; ++fr) {
                #pragma unroll
                for (int i = 0; i < 4; ++i) {
                    int row = (wr * 2 + fr) * 16 + g * 4 + i;
                    float v = acc[fr][fc][i] + bv;
                    v = v > 0.f ? v : 0.f;
                    ((unsigned short*)Atile)[((row * 32 + c) ^ (row & 7)) * 8 + el] =
                        (unsigned short)f2bf(v);
                }
            }
        }
    }
    __syncthreads();

    // ---- phase 2: GRU (K=256 over [x|hidden]) ----
    for (int ot = 0; ot < 2; ++ot) {
        const int o0 = ot * 64;
        f32x4 rr[2][2] = {}, zz[2][2] = {}, ni[2][2] = {}, nh[2][2] = {};
        #pragma unroll
        for (int ks = 0; ks < 4; ++ks) {  // x part: wih
            bf16x8 af[2], brr[2], bzz[2], bnn[2];
            #pragma unroll
            for (int fr = 0; fr < 2; ++fr)
                af[fr] = lda_frag(Atile, 32, (wr * 2 + fr) * 16 + m, ks * 4 + g);
            #pragma unroll
            for (int fc = 0; fc < 2; ++fc) {
                int ro = o0 + (wc * 2 + fc) * 16 + m;
                brr[fc] = ldb_frag(wih, ro, 128, ks * 4 + g);
                bzz[fc] = ldb_frag(wih, 128 + ro, 128, ks * 4 + g);
                bnn[fc] = ldb_frag(wih, 256 + ro, 128, ks * 4 + g);
            }
            #pragma unroll
            for (int fr = 0; fr < 2; ++fr)
                #pragma unroll
                for (int fc = 0; fc < 2; ++fc) {
                    rr[fr][fc] = __builtin_amdgcn_mfma_f32_16x16x32_bf16(af[fr], brr[fc], rr[fr][fc], 0, 0, 0);
                    zz[fr][fc] = __builtin_amdgcn_mfma_f32_16x16x32_bf16(af[fr], bzz[fc], zz[fr][fc], 0, 0, 0);
                    ni[fr][fc] = __builtin_amdgcn_mfma_f32_16x16x32_bf16(af[fr], bnn[fc], ni[fr][fc], 0, 0, 0);
                }
        }
        #pragma unroll
        for (int ks = 0; ks < 4; ++ks) {  // hidden part: whh
            bf16x8 af[2], brr[2], bzz[2], bnn[2];
            #pragma unroll
            for (int fr = 0; fr < 2; ++fr)
                af[fr] = lda_frag(Atile, 32, (wr * 2 + fr) * 16 + m, 16 + ks * 4 + g);
            #pragma unroll
            for (int fc = 0; fc < 2; ++fc) {
                int ro = o0 + (wc * 2 + fc) * 16 + m;
                brr[fc] = ldb_frag(whh, ro, 128, ks * 4 + g);
                bzz[fc] = ldb_frag(whh, 128 + ro, 128, ks * 4 + g);
                bnn[fc] = ldb_frag(whh, 256 + ro, 128, ks * 4 + g);
            }
            #pragma unroll
            for (int fr = 0; fr < 2; ++fr)
                #pragma unroll
                for (int fc = 0; fc < 2; ++fc) {
                    rr[fr][fc] = __builtin_amdgcn_mfma_f32_16x16x32_bf16(af[fr], brr[fc], rr[fr][fc], 0, 0, 0);
                    zz[fr][fc] = __builtin_amdgcn_mfma_f32_16x16x32_bf16(af[fr], bzz[fc], zz[fr][fc], 0, 0, 0);
                    nh[fr][fc] = __builtin_amdgcn_mfma_f32_16x16x32_bf16(af[fr], bnn[fc], nh[fr][fc], 0, 0, 0);
                }
        }
        #pragma unroll
        for (int fc = 0; fc < 2; ++fc) {
            int c = o0 + (wc * 2 + fc) * 16 + m;
            float brz = b_ih[c] + b_hh[c];
            float bzz2 = b_ih[128 + c] + b_hh[128 + c];
            float bin = b_ih[256 + c], bhn = b_hh[256 + c];
            #pragma unroll
            for (int fr = 0; fr < 2; ++fr) {
                #pragma unroll
                for (int i = 0; i < 4; ++i) {
                    int row = r0 + (wr * 2 + fr) * 16 + g * 4 + i;
                    float rv = sigmoidf_(rr[fr][fc][i] + brz);
                    float zv = sigmoidf_(zz[fr][fc][i] + bzz2);
                    float ng = tanhf(ni[fr][fc][i] + bin + rv * (nh[fr][fc][i] + bhn));
                    float hp = hidden[(size_t)row * 128 + c];
                    float hv = ng + zv * (hp - ng);
                    hb[(size_t)row * 128 + c] = (unsigned short)f2bf(hv);
                }
            }
        }
    }
}

// ---------------------------------------------------------------------------
// Fused lse1 + lse2: lt = relu(latent@w1^T) -> LDS; le = lt@w2^T -> bf16 global.
__global__ __launch_bounds__(256, 2)
void lse12(const float* __restrict__ latent,
           const unsigned short* __restrict__ w1b, const float* __restrict__ b1,
           const unsigned short* __restrict__ w2b, const float* __restrict__ b2,
           unsigned short* __restrict__ leb)
{
    __shared__ uint4 Alat[64 * 8];
    __shared__ uint4 Alt[64 * 16];
    const int tid = threadIdx.x;
    const int r0 = blockIdx.x * 64;

    for (int idx = tid; idx < 64 * 8; idx += 256) {
        int row = idx >> 3, c = idx & 7;
        const float4* p = (const float4*)(latent + (size_t)(r0 + row) * 64 + c * 8);
        Alat[(row * 8 + c) ^ (row & 7)] = pack8(p[0], p[1]);
    }
    __syncthreads();

    const int lane = tid & 63, w = tid >> 6;
    const int wr = w >> 1, wc = w & 1;
    const int m = lane & 15, g = lane >> 4;

    // lse1: K=64, O=128 -> Alt
    for (int ot = 0; ot < 2; ++ot) {
        const int o0 = ot * 64;
        f32x4 acc[2][2] = {};
        #pragma unroll
        for (int ks = 0; ks < 2; ++ks) {
            bf16x8 af[2], bf[2];
            #pragma unroll
            for (int fr = 0; fr < 2; ++fr)
                af[fr] = lda_frag(Alat, 8, (wr * 2 + fr) * 16 + m, ks * 4 + g);
            #pragma unroll
            for (int fc = 0; fc < 2; ++fc)
                bf[fc] = ldb_frag(w1b, o0 + (wc * 2 + fc) * 16 + m, 64, ks * 4 + g);
            #pragma unroll
            for (int fr = 0; fr < 2; ++fr)
                #pragma unroll
                for (int fc = 0; fc < 2; ++fc)
                    acc[fr][fc] = __builtin_amdgcn_mfma_f32_16x16x32_bf16(
                        af[fr], bf[fc], acc[fr][fc], 0, 0, 0);
        }
        #pragma unroll
        for (int fc = 0; fc < 2; ++fc) {
            int col = o0 + (wc * 2 + fc) * 16 + m;
            float bv = b1[col];
            int c = col >> 3, el = col & 7;
            #pragma unroll
            for (int fr = 0; fr < 2; ++fr) {
                #pragma unroll
                for (int i = 0; i < 4; ++i) {
                    int row = (wr * 2 + fr) * 16 + g * 4 + i;
                    float v = acc[fr][fc][i] + bv;
                    v = v > 0.f ? v : 0.f;
                    ((unsigned short*)Alt)[((row * 16 + c) ^ (row & 7)) * 8 + el] =
                        (unsigned short)f2bf(v);
                }
            }
        }
    }
    __syncthreads();

    // lse2: K=128, O=128 -> leb
    for (int ot = 0; ot < 2; ++ot) {
        const int o0 = ot * 64;
        f32x4 acc[2][2] = {};
        #pragma unroll
        for (int ks = 0; ks < 4; ++ks) {
            bf16x8 af[2], bf[2];
            #pragma unroll
            for (int fr = 0; fr < 2; ++fr)
                af[fr] = lda_frag(Alt, 16, (wr * 2 + fr) * 16 + m, ks * 4 + g);
            #pragma unroll
            for (int fc = 0; fc < 2; ++fc)
                bf[fc] = ldb_frag(w2b, o0 + (wc * 2 + fc) * 16 + m, 128, ks * 4 + g);
            #pragma unroll
            for (int fr = 0; fr < 2; ++fr)
                #pragma unroll
                for (int fc = 0; fc < 2; ++fc)
                    acc[fr][fc] = __builtin_amdgcn_mfma_f32_16x16x32_bf16(
                        af[fr], bf[fc], acc[fr][fc], 0, 0, 0);
        }
        #pragma unroll
        for (int fc = 0; fc < 2; ++fc) {
            int col = o0 + (wc * 2 + fc) * 16 + m;
            float bv = b2[col];
            #pragma unroll
            for (int fr = 0; fr < 2; ++fr) {
                #pragma unroll
                for (int i = 0; i < 4; ++i) {
                    int rowl = (wr * 2 + fr) * 16 + g * 4 + i;
                    float v = acc[fr][fc][i] + bv;
                    leb[(size_t)(r0 + rowl) * 128 + col] = (unsigned short)f2bf(v);
                }
            }
        }
    }
}

// ---------------------------------------------------------------------------
// me1 GEMM (K=256, O=256) + BN partial sums + fused hl projection (fc2[:, :256]).
__global__ __launch_bounds__(256, 2)
void me1_stats(const unsigned short* __restrict__ hb, const unsigned short* __restrict__ leb,
               const unsigned short* __restrict__ W, const float* __restrict__ bias,
               const unsigned short* __restrict__ f2w, const float* __restrict__ fc2_b,
               unsigned short* __restrict__ t1,
               float* __restrict__ psum, float* __restrict__ psq,
               float* __restrict__ hl)
{
    __shared__ uint4 Atile[64 * 32];
    __shared__ float sredS[2][2][2][16];
    __shared__ float sredQ[2][2][2][16];
    const int tid = threadIdx.x;
    const int r0 = blockIdx.x * 64;

    for (int idx = tid; idx < 64 * 32; idx += 256) {
        int row = idx >> 5, c = idx & 31;
        const unsigned short* src = (c < 16)
            ? hb + (size_t)(r0 + row) * 128 + c * 8
            : leb + (size_t)(r0 + row) * 128 + (c - 16) * 8;
        Atile[(row * 32 + c) ^ (row & 7)] = *(const uint4*)src;
    }
    __syncthreads();

    const int lane = tid & 63, w = tid >> 6;
    const int wr = w >> 1, wc = w & 1;
    const int m = lane & 15, g = lane >> 4;

    for (int ot = 0; ot < 4; ++ot) {
        const int o0 = ot * 64;
        f32x4 acc[2][2] = {};
        #pragma unroll
        for (int ks = 0; ks < 8; ++ks) {
            bf16x8 af[2], bf[2];
            #pragma unroll
            for (int fr = 0; fr < 2; ++fr)
                af[fr] = lda_frag(Atile, 32, (wr * 2 + fr) * 16 + m, ks * 4 + g);
            #pragma unroll
            for (int fc = 0; fc < 2; ++fc)
                bf[fc] = ldb_frag(W, o0 + (wc * 2 + fc) * 16 + m, 256, ks * 4 + g);
            #pragma unroll
            for (int fr = 0; fr < 2; ++fr)
                #pragma unroll
                for (int fc = 0; fc < 2; ++fc)
                    acc[fr][fc] = __builtin_amdgcn_mfma_f32_16x16x32_bf16(
                        af[fr], bf[fc], acc[fr][fc], 0, 0, 0);
        }
        #pragma unroll
        for (int fc = 0; fc < 2; ++fc) {
            int col = o0 + (wc * 2 + fc) * 16 + m;
            float bv = bias[col];
            float s = 0.f, q = 0.f;
            #pragma unroll
            for (int fr = 0; fr < 2; ++fr) {
                #pragma unroll
                for (int i = 0; i < 4; ++i) {
                    int rowl = (wr * 2 + fr) * 16 + g * 4 + i;
                    float v = acc[fr][fc][i] + bv;
                    t1[(size_t)(r0 + rowl) * 256 + col] = (unsigned short)f2bf(v);
                    s += v; q += v * v;
                }
            }
            s += __shfl_xor(s, 16); s += __shfl_xor(s, 32);
            q += __shfl_xor(q, 16); q += __shfl_xor(q, 32);
            if (lane < 16) { sredS[wr][wc][fc][m] = s; sredQ[wr][wc][fc][m] = q; }
        }
        __syncthreads();
        if (tid < 64) {
            int wcfc = tid >> 4, mm = tid & 15;
            int wc2 = wcfc >> 1, fc2 = wcfc & 1;
            psum[(size_t)blockIdx.x * 256 + o0 + tid] =
                sredS[0][wc2][fc2][mm] + sredS[1][wc2][fc2][mm];
            psq[(size_t)blockIdx.x * 256 + o0 + tid] =
                sredQ[0][wc2][fc2][mm] + sredQ[1][wc2][fc2][mm];
        }
        __syncthreads();  // protect sred reuse next ot
    }

    // ---- fused hl: each wave handles rows [w*16, w*16+16), cols 0..29 ----
    {
        f32x4 acc[2] = {};
        #pragma unroll
        for (int ks = 0; ks < 8; ++ks) {
            bf16x8 af = lda_frag(Atile, 32, w * 16 + m, ks * 4 + g);
            bf16x8 bf[2];
            #pragma unroll
            for (int fc = 0; fc < 2; ++fc) {
                int col = fc * 16 + m;
                bf[fc] = (col < NA_) ? ldb_frag(f2w, col, 1280, ks * 4 + g)
                                     : bf16x8{};
            }
            #pragma unroll
            for (int fc = 0; fc < 2; ++fc)
                acc[fc] = __builtin_amdgcn_mfma_f32_16x16x32_bf16(af, bf[fc], acc[fc], 0, 0, 0);
        }
        #pragma unroll
        for (int fc = 0; fc < 2; ++fc) {
            int col = fc * 16 + m;
            if (col < NA_) {
                float bv = fc2_b[col];
                #pragma unroll
                for (int i = 0; i < 4; ++i) {
                    int row = r0 + w * 16 + g * 4 + i;
                    hl[(size_t)row * NA_ + col] = acc[fc][i] + bv;
                }
            }
        }
    }
}

__global__ __launch_bounds__(256)
void bn_final_kernel(const float* __restrict__ psum, const float* __restrict__ psq,
                     const float* __restrict__ g, const float* __restrict__ beta,
                     float* __restrict__ scale, float* __restrict__ shift)
{
    int f = threadIdx.x;
    float s = 0.f, ss = 0.f;
    #pragma unroll 8
    for (int b = 0; b < 512; ++b) { s += psum[(size_t)b * 256 + f]; ss += psq[(size_t)b * 256 + f]; }
    float mean = s / (float)R_;
    float var = ss / (float)R_ - mean * mean;
    float istd = rsqrtf(var + 1e-5f);
    float sc = g[f] * istd;
    scale[f] = sc;
    shift[f] = beta[f] - mean * sc;
}

// ---------------------------------------------------------------------------
// me2 GEMM with BN+lrelu in A-staging; epilogue computes pm (bf16).
__global__ __launch_bounds__(256, 2)
void me2pm(const unsigned short* __restrict__ t1,
           const float* __restrict__ scale, const float* __restrict__ shift,
           const unsigned short* __restrict__ W, const float* __restrict__ bias,
           const float* __restrict__ eps, unsigned short* __restrict__ pm)
{
    __shared__ uint4 Atile[64 * 32];
    __shared__ float sc_s[256], sh_s[256];
    const int tid = threadIdx.x;
    const int r0 = blockIdx.x * 64;

    sc_s[tid] = scale[tid];
    sh_s[tid] = shift[tid];
    __syncthreads();

    for (int idx = tid; idx < 64 * 32; idx += 256) {
        int row = idx >> 5, c = idx & 31;
        uint4 u = *(const uint4*)(t1 + (size_t)(r0 + row) * 256 + c * 8);
        unsigned int vv[4] = {u.x, u.y, u.z, u.w};
        float f[8];
        #pragma unroll
        for (int q2 = 0; q2 < 4; ++q2) {
            f[2 * q2]     = __uint_as_float((vv[q2] & 0xffffu) << 16);
            f[2 * q2 + 1] = __uint_as_float(vv[q2] & 0xffff0000u);
        }
        int k = c * 8;
        #pragma unroll
        for (int j = 0; j < 8; ++j) {
            float v = f[j] * sc_s[k + j] + sh_s[k + j];
            f[j] = v > 0.f ? v : 0.01f * v;
        }
        uint4 r;
        r.x = pack2(f[0], f[1]); r.y = pack2(f[2], f[3]);
        r.z = pack2(f[4], f[5]); r.w = pack2(f[6], f[7]);
        Atile[(row * 32 + c) ^ (row & 7)] = r;
    }
    __syncthreads();

    const int lane = tid & 63, w = tid >> 6;
    const int wr = w >> 1, wc = w & 1;
    const int m = lane & 15, g = lane >> 4;

    float msave[2][2][4];
    for (int ot = 0; ot < 2; ++ot) {
        const int o0 = ot * 64;
        f32x4 acc[2][2] = {};
        #pragma unroll
        for (int ks = 0; ks < 8; ++ks) {
            bf16x8 af[2], bf[2];
            #pragma unroll
            for (int fr = 0; fr < 2; ++fr)
                af[fr] = lda_frag(Atile, 32, (wr * 2 + fr) * 16 + m, ks * 4 + g);
            #pragma unroll
            for (int fc = 0; fc < 2; ++fc)
                bf[fc] = ldb_frag(W, o0 + (wc * 2 + fc) * 16 + m, 256, ks * 4 + g);
            #pragma unroll
            for (int fr = 0; fr < 2; ++fr)
                #pragma unroll
                for (int fc = 0; fc < 2; ++fc)
                    acc[fr][fc] = __builtin_amdgcn_mfma_f32_16x16x32_bf16(
                        af[fr], bf[fc], acc[fr][fc], 0, 0, 0);
        }
        #pragma unroll
        for (int fc = 0; fc < 2; ++fc) {
            int cp = (wc * 2 + fc) * 16 + m;
            float bv = bias[o0 + cp];
            #pragma unroll
            for (int fr = 0; fr < 2; ++fr) {
                #pragma unroll
                for (int i = 0; i < 4; ++i) {
                    float v = acc[fr][fc][i] + bv;
                    v = v > 0.f ? v : 0.01f * v;
                    if (ot == 0) {
                        msave[fc][fr][i] = fminf(fmaxf(v, -1.f), 1.f);
                    } else {
                        float sd = fminf(fmaxf(v, 0.5f), 1.f);
                        int row = r0 + (wr * 2 + fr) * 16 + g * 4 + i;
                        float e = eps[(size_t)row * 64 + cp];
                        pm[(size_t)row * 64 + cp] =
                            (unsigned short)f2bf(msave[fc][fr][i] + sd * e);
                    }
                }
            }
        }
    }
}

// ---------------------------------------------------------------------------
// Fused kq_norm + v1 + v2. A1 = [h|pm] (K=192) staged once.
// Phase 0: kh=norm(k(h)), qh=norm(q(pm)).
// Phase 1: t3 = lrelu(v1(A1)) -> LDS. Phase 2: value = v2(t3) -> bf16.
__global__ __launch_bounds__(256, 2)
void kqv12(const unsigned short* __restrict__ hb, const unsigned short* __restrict__ pmb,
           const unsigned short* __restrict__ kwb, const float* __restrict__ k_b,
           const unsigned short* __restrict__ qwb, const float* __restrict__ q_b,
           const unsigned short* __restrict__ v1w, const float* __restrict__ v1_b,
           const unsigned short* __restrict__ v2w, const float* __restrict__ v2_b,
           float* __restrict__ kh, float* __restrict__ qh,
           unsigned short* __restrict__ valb)
{
    __shared__ uint4 A1[64 * 24];   // [h(chunks 0..15) | pm(chunks 16..23)]
    __shared__ uint4 A3[64 * 32];   // t3
    const int tid = threadIdx.x;
    const int r0 = blockIdx.x * 64;

    for (int idx = tid; idx < 64 * 24; idx += 256) {
        int row = idx / 24, c = idx - row * 24;
        const unsigned short* src = (c < 16)
            ? hb + (size_t)(r0 + row) * 128 + c * 8
            : pmb + (size_t)(r0 + row) * 64 + (c - 16) * 8;
        A1[(row * 24 + c) ^ (row & 7)] = *(const uint4*)src;
    }
    __syncthreads();

    const int lane = tid & 63, w = tid >> 6;
    const int wr = w >> 1, wc = w & 1;
    const int m = lane & 15, g = lane >> 4;

    // ---- phase 0: kq + cosine norm. waves 0-1: k over h; waves 2-3: q over pm.
    {
        const bool isq = w >= 2;
        const int half = w & 1;
        f32x4 acc[2][2] = {};
        const int nks = isq ? 2 : 4;
        for (int ks = 0; ks < nks; ++ks) {
            bf16x8 af[2], bf[2];
            #pragma unroll
            for (int fr = 0; fr < 2; ++fr) {
                int row = half * 32 + fr * 16 + m;
                int c = (isq ? 16 : 0) + ks * 4 + g;
                af[fr] = lda_frag(A1, 24, row, c);
            }
            #pragma unroll
            for (int fc = 0; fc < 2; ++fc) {
                int brow = fc * 16 + m;
                bf[fc] = isq ? ldb_frag(qwb, brow, 64, ks * 4 + g)
                             : ldb_frag(kwb, brow, 128, ks * 4 + g);
            }
            #pragma unroll
            for (int fr = 0; fr < 2; ++fr)
                #pragma unroll
                for (int fc = 0; fc < 2; ++fc)
                    acc[fr][fc] = __builtin_amdgcn_mfma_f32_16x16x32_bf16(
                        af[fr], bf[fc], acc[fr][fc], 0, 0, 0);
        }
        const float* bias = isq ? q_b : k_b;
        float b0 = bias[m], b1 = bias[16 + m];
        float* outp = isq ? qh : kh;
        #pragma unroll
        for (int fr = 0; fr < 2; ++fr) {
            #pragma unroll
            for (int i = 0; i < 4; ++i) {
                float v0 = acc[fr][0][i] + b0;
                float v1 = acc[fr][1][i] + b1;
                float ss = v0 * v0 + v1 * v1;
                ss += __shfl_xor(ss, 1); ss += __shfl_xor(ss, 2);
                ss += __shfl_xor(ss, 4); ss += __shfl_xor(ss, 8);
                float inv = 1.f / fmaxf(sqrtf(ss), 1e-8f);
                int row = r0 + half * 32 + fr * 16 + g * 4 + i;
                outp[(size_t)row * 32 + m] = v0 * inv;
                outp[(size_t)row * 32 + 16 + m] = v1 * inv;
            }
        }
    }

    // ---- phase 1: v1 (K=192, O=256) -> A3 ----
    for (int ot = 0; ot < 4; ++ot) {
        const int o0 = ot * 64;
        f32x4 acc[2][2] = {};
        #pragma unroll
        for (int ks = 0; ks < 6; ++ks) {
            bf16x8 af[2], bf[2];
            #pragma unroll
            for (int fr = 0; fr < 2; ++fr)
                af[fr] = lda_frag(A1, 24, (wr * 2 + fr) * 16 + m, ks * 4 + g);
            #pragma unroll
            for (int fc = 0; fc < 2; ++fc)
                bf[fc] = ldb_frag(v1w, o0 + (wc * 2 + fc) * 16 + m, 192, ks * 4 + g);
            #pragma unroll
            for (int fr = 0; fr < 2; ++fr)
                #pragma unroll
                for (int fc = 0; fc < 2; ++fc)
                    acc[fr][fc] = __builtin_amdgcn_mfma_f32_16x16x32_bf16(
                        af[fr], bf[fc], acc[fr][fc], 0, 0, 0);
        }
        #pragma unroll
        for (int fc = 0; fc < 2; ++fc) {
            int col = o0 + (wc * 2 + fc) * 16 + m;
            float bv = v1_b[col];
            int c = col >> 3, el = col & 7;
            #pragma unroll
            for (int fr = 0; fr < 2; ++fr) {
                #pragma unroll
                for (int i = 0; i < 4; ++i) {
                    int row = (wr * 2 + fr) * 16 + g * 4 + i;
                    float v = acc[fr][fc][i] + bv;
                    v = v > 0.f ? v : 0.01f * v;
                    ((unsigned short*)A3)[((row * 32 + c) ^ (row & 7)) * 8 + el] =
                        (unsigned short)f2bf(v);
                }
            }
        }
    }
    __syncthreads();

    // ---- phase 2: v2 (K=256, O=64) -> valb ----
    {
        f32x4 acc[2][2] = {};
        #pragma unroll
        for (int ks = 0; ks < 8; ++ks) {
            bf16x8 af[2], bf[2];
            #pragma unroll
            for (int fr = 0; fr < 2; ++fr)
                af[fr] = lda_frag(A3, 32, (wr * 2 + fr) * 16 + m, ks * 4 + g);
            #pragma unroll
            for (int fc = 0; fc < 2; ++fc)
                bf[fc] = ldb_frag(v2w, (wc * 2 + fc) * 16 + m, 256, ks * 4 + g);
            #pragma unroll
            for (int fr = 0; fr < 2; ++fr)
                #pragma unroll
                for (int fc = 0; fc < 2; ++fc)
                    acc[fr][fc] = __builtin_amdgcn_mfma_f32_16x16x32_bf16(
                        af[fr], bf[fc], acc[fr][fc], 0, 0, 0);
        }
        #pragma unroll
        for (int fc = 0; fc < 2; ++fc) {
            int col = (wc * 2 + fc) * 16 + m;
            float bv = v2_b[col];
            #pragma unroll
            for (int fr = 0; fr < 2; ++fr) {
                #pragma unroll
                for (int i = 0; i < 4; ++i) {
                    int rowl = (wr * 2 + fr) * 16 + g * 4 + i;
                    float v = acc[fr][fc][i] + bv;
                    valb[(size_t)(r0 + rowl) * 64 + col] = (unsigned short)f2bf(v);
                }
            }
        }
    }
}

// ---------------------------------------------------------------------------
// vproj[r][na] = w2[na, 256+64*(r%16) .. +64] . value[r]   (value bf16, w2 f32)
__global__ __launch_bounds__(256)
void vproj_kernel(const unsigned short* __restrict__ value, const float* __restrict__ w2,
                  float* __restrict__ vproj)
{
    __shared__ float w2s[NA_][65];
    __shared__ float val_s[64][65];
    const int tid = threadIdx.x;
    const int j = blockIdx.x & 15;
    const int b0 = (blockIdx.x >> 4) * 64;

    for (int idx = tid; idx < NA_ * 64; idx += 256) {
        int na = idx >> 6, k = idx & 63;
        w2s[na][k] = w2[(size_t)na * 1280 + 256 + j * 64 + k];
    }
    for (int idx = tid; idx < 64 * 64; idx += 256) {
        int bl = idx >> 6, k = idx & 63;
        val_s[bl][k] = bf2f(value[((size_t)(b0 + bl) * 16 + j) * 64 + k]);
    }
    __syncthreads();

    for (int task = tid; task < 64 * NA_; task += 256) {
        int bl = task / NA_, na = task - bl * NA_;
        float acc = 0.f;
        #pragma unroll 16
        for (int k = 0; k < 64; ++k) acc = fmaf(val_s[bl][k], w2s[na][k], acc);
        vproj[((size_t)(b0 + bl) * 16 + j) * NA_ + na] = acc;
    }
}

// Per batch: cosine logits (16x16), softmax over j, zero diag, combine.
__global__ __launch_bounds__(256)
void attn_combine(const float* __restrict__ kh, const float* __restrict__ qh,
                  const float* __restrict__ vproj, const float* __restrict__ hl,
                  float* __restrict__ outv)
{
    __shared__ float kh_s[16][33], qh_s[16][33];
    __shared__ float al_s[16][16];
    __shared__ float vp_s[16][NA_];
    const int tid = threadIdx.x;
    const size_t rb = (size_t)blockIdx.x * 16;

    for (int idx = tid; idx < 512; idx += 256) {
        int r = idx >> 5, a = idx & 31;
        kh_s[r][a] = kh[rb * 32 + idx];
        qh_s[r][a] = qh[rb * 32 + idx];
    }
    for (int idx = tid; idx < 16 * NA_; idx += 256)
        vp_s[idx / NA_][idx % NA_] = vproj[rb * NA_ + idx];
    __syncthreads();

    {
        int i = tid >> 4, j = tid & 15;
        float l = 0.f;
        #pragma unroll
        for (int a = 0; a < 32; ++a) l = fmaf(kh_s[i][a], qh_s[j][a], l);
        float mx = l;
        #pragma unroll
        for (int mm = 8; mm >= 1; mm >>= 1) mx = fmaxf(mx, __shfl_xor(mx, mm));
        float e = expf(l - mx);
        float s = e;
        #pragma unroll
        for (int mm = 8; mm >= 1; mm >>= 1) s += __shfl_xor(s, mm);
        float a = e / s;
        if (i == j) a = 0.f;
        al_s[i][j] = a;
    }
    __syncthreads();

    for (int task = tid; task < 16 * NA_; task += 256) {
        int i = task / NA_, na = task - i * NA_;
        float acc = hl[(rb + i) * NA_ + na];
        #pragma unroll
        for (int j = 0; j < 16; ++j) acc = fmaf(al_s[i][j], vp_s[j][na], acc);
        outv[(rb + i) * NA_ + na] = acc;
    }
}

extern "C" void kernel_launch(void* const* d_in, const int* in_sizes, int n_in,
                              void* d_out, int out_size, void* d_ws, size_t ws_size,
                              hipStream_t stream)
{
    (void)in_sizes; (void)n_in; (void)out_size; (void)ws_size;
    const float* inputs  = (const float*)d_in[0];
    const float* hidden  = (const float*)d_in[1];
    const float* latent  = (const float*)d_in[2];
    const float* eps     = (const float*)d_in[3];
    const float* fc1_w   = (const float*)d_in[4];
    const float* fc1_b   = (const float*)d_in[5];
    const float* w_ih    = (const float*)d_in[6];
    const float* w_hh    = (const float*)d_in[7];
    const float* b_ih    = (const float*)d_in[8];
    const float* b_hh    = (const float*)d_in[9];
    const float* lse_w1  = (const float*)d_in[10];
    const float* lse_b1  = (const float*)d_in[11];
    const float* lse_w2  = (const float*)d_in[12];
    const float* lse_b2  = (const float*)d_in[13];
    const float* me_w1   = (const float*)d_in[14];
    const float* me_b1   = (const float*)d_in[15];
    const float* me_g    = (const float*)d_in[16];
    const float* me_beta = (const float*)d_in[17];
    const float* me_w2   = (const float*)d_in[18];
    const float* me_b2   = (const float*)d_in[19];
    const float* k_w     = (const float*)d_in[20];
    const float* k_b     = (const float*)d_in[21];
    const float* q_w     = (const float*)d_in[22];
    const float* q_b     = (const float*)d_in[23];
    const float* v_w1    = (const float*)d_in[24];
    const float* v_b1    = (const float*)d_in[25];
    const float* v_w2    = (const float*)d_in[26];
    const float* v_b2    = (const float*)d_in[27];
    const float* fc2_w   = (const float*)d_in[28];
    const float* fc2_b   = (const float*)d_in[29];

    const size_t R = R_;
    // Workspace layout: bf16 activations, bf16 weights, then f32 buffers.
    unsigned short* bws = (unsigned short*)d_ws;
    unsigned short* hb   = bws;               // R*128
    unsigned short* leb  = hb + R * 128;      // R*128
    unsigned short* t1b  = leb + R * 128;     // R*256
    unsigned short* pmb  = t1b + R * 256;     // R*64
    unsigned short* valb = pmb + R * 64;      // R*64
    unsigned short* wb   = valb + R * 64;     // 347648 (bf16 weights)
    float* fws  = (float*)(wb + woff::total);
    float* khf  = fws;                 // R*32
    float* qhf  = khf + R * 32;        // R*32
    float* hlf  = qhf + R * 32;        // R*30
    float* vpf  = hlf + R * 30;        // R*30
    float* psum = vpf + R * 30;        // 512*256
    float* psq  = psum + 512 * 256;    // 512*256
    float* scale = psq + 512 * 256;    // 256
    float* shift = scale + 256;        // 256

    dim3 blk(256);
    dim3 g512(R_ / 64);

    // 0) weights -> bf16 (once per call; cheap)
    wcvt_kernel<<<dim3((woff::total + 255) / 256), blk, 0, stream>>>(
        fc1_w, w_ih, w_hh, lse_w1, lse_w2, me_w1, me_w2, k_w, q_w, v_w1, v_w2, fc2_w, wb);

    // 1) x = relu(fc1(inputs)) [LDS]; h = GRU(x, hidden) -> bf16
    fc1_gru<<<g512, blk, 0, stream>>>(inputs, hidden, wb + woff::fc1, fc1_b,
                                      wb + woff::ih, wb + woff::hh, b_ih, b_hh, hb);
    // 2) lt = relu(lse1(latent)) [LDS]; le = lse2(lt) -> bf16
    lse12<<<g512, blk, 0, stream>>>(latent, wb + woff::l1, lse_b1,
                                    wb + woff::l2, lse_b2, leb);
    // 3) t1 = me1(cat(h,le)) -> bf16 + BN partial stats + hl projection
    me1_stats<<<g512, blk, 0, stream>>>(hb, leb, wb + woff::m1, me_b1,
                                        wb + woff::f2, fc2_b, t1b, psum, psq, hlf);
    bn_final_kernel<<<dim3(1), blk, 0, stream>>>(psum, psq, me_g, me_beta, scale, shift);
    // 4) pm = clip(lrelu(me2(bn(t1)))) + std*eps -> bf16
    me2pm<<<g512, blk, 0, stream>>>(t1b, scale, shift, wb + woff::m2, me_b2, eps, pmb);
    // 5) kh/qh = norm(k(h))/norm(q(pm)); t3 = lrelu(v1([h|pm])) [LDS]; value = v2(t3)
    kqv12<<<g512, blk, 0, stream>>>(hb, pmb, wb + woff::kw, k_b, wb + woff::qw, q_b,
                                    wb + woff::v1, v_b1, wb + woff::v2, v_b2,
                                    khf, qhf, valb);
    // 6) vproj = per-agent fc2_w slice . value
    vproj_kernel<<<dim3(16 * (BSB_ / 64)), blk, 0, stream>>>(valb, fc2_w, vpf);
    // 7) softmax + combine -> out
    attn_combine<<<dim3(BSB_), blk, 0, stream>>>(khf, qhf, vpf, hlf, (float*)d_out);
}